// Round 1
// baseline (2612.993 us; speedup 1.0000x reference)
//
#include <hip/hip_runtime.h>
#include <hip/hip_bf16.h>
#include <cstddef>

#define BB 4
#define LL 2048
#define DM 256
#define DN 512
#define EE 1024
#define NS 16
#define RK 16

__device__ __forceinline__ float fsilu(float x) { return x / (1.0f + __expf(-x)); }
__device__ __forceinline__ float fsoftplus(float x) { return x > 20.0f ? x : log1pf(__expf(x)); }

// ---------------------------------------------------------------------------
// in_proj: xz[b][e][l] = sum_d in_w[e][d] * h[b][l][d]
// tile 128e x 128l, K-step 32, 256 threads, 8x8 microtile
// ---------------------------------------------------------------------------
__global__ __launch_bounds__(256) void in_proj_kernel(
    const float* __restrict__ h, const float* __restrict__ w, float* __restrict__ xz) {
  __shared__ float hs[32][132];   // [k][l]
  __shared__ float wsm[32][132];  // [k][e]
  const int b = blockIdx.z;
  const int e0 = blockIdx.y * 128;
  const int l0 = blockIdx.x * 128;
  const int tid = threadIdx.x;
  const int tx = tid & 15;  // l
  const int ty = tid >> 4;  // e
  float acc[8][8] = {};
  for (int dk = 0; dk < DM; dk += 32) {
#pragma unroll
    for (int it = 0; it < 16; it++) {
      int idx = it * 256 + tid;
      int i = idx >> 5;  // row (l or e), 0..127
      int j = idx & 31;  // k
      hs[j][i] = h[((size_t)b * LL + l0 + i) * DM + dk + j];
      wsm[j][i] = w[(size_t)(e0 + i) * DM + dk + j];
    }
    __syncthreads();
#pragma unroll
    for (int kk = 0; kk < 32; kk++) {
      const float4 h0 = *(const float4*)(&hs[kk][tx * 8]);
      const float4 h1 = *(const float4*)(&hs[kk][tx * 8 + 4]);
      const float4 w0 = *(const float4*)(&wsm[kk][ty * 8]);
      const float4 w1 = *(const float4*)(&wsm[kk][ty * 8 + 4]);
      const float hv[8] = {h0.x, h0.y, h0.z, h0.w, h1.x, h1.y, h1.z, h1.w};
      const float wv[8] = {w0.x, w0.y, w0.z, w0.w, w1.x, w1.y, w1.z, w1.w};
#pragma unroll
      for (int a = 0; a < 8; a++)
#pragma unroll
        for (int c = 0; c < 8; c++) acc[a][c] = fmaf(wv[a], hv[c], acc[a][c]);
    }
    __syncthreads();
  }
#pragma unroll
  for (int a = 0; a < 8; a++) {
    float* orow = xz + ((size_t)b * EE + e0 + ty * 8 + a) * LL + l0 + tx * 8;
    *(float4*)(orow) = make_float4(acc[a][0], acc[a][1], acc[a][2], acc[a][3]);
    *(float4*)(orow + 4) = make_float4(acc[a][4], acc[a][5], acc[a][6], acc[a][7]);
  }
}

// ---------------------------------------------------------------------------
// fused conv+silu -> x_dbl(48) -> delta(softplus). One block = (b, 32 l's).
// REV=1: backward branch — conv taps at t..t+3 with reversed weights.
// Writes delta (B,DN,L), Bc (B,L,16), Cc (B,L,16).
// ---------------------------------------------------------------------------
template <int REV>
__global__ __launch_bounds__(256) void convproj_kernel(
    const float* __restrict__ xz, const float* __restrict__ conv_w,
    const float* __restrict__ conv_b, const float* __restrict__ x_w,
    const float* __restrict__ dt_w, const float* __restrict__ dt_b,
    float* __restrict__ delta_out, float* __restrict__ Bc, float* __restrict__ Cc) {
  __shared__ float xt[DN][32];   // conv+silu output tile, 64 KiB
  __shared__ float dtv[RK][32];  // dt rows
  const int b = blockIdx.y;
  const int l0 = blockIdx.x * 32;
  const int tid = threadIdx.x;
  const int lc = tid & 31;
  const int l = l0 + lc;

  // conv + silu
#pragma unroll 4
  for (int i = 0; i < 64; i++) {
    int d = i * 8 + (tid >> 5);
    const float* base = xz + ((size_t)b * EE + d) * LL;
    float w0 = conv_w[d * 4 + 0], w1 = conv_w[d * 4 + 1];
    float w2 = conv_w[d * 4 + 2], w3 = conv_w[d * 4 + 3];
    float acc = conv_b[d];
    if (REV) {
      acc = fmaf(w3, base[l], acc);
      if (l + 1 < LL) acc = fmaf(w2, base[l + 1], acc);
      if (l + 2 < LL) acc = fmaf(w1, base[l + 2], acc);
      if (l + 3 < LL) acc = fmaf(w0, base[l + 3], acc);
    } else {
      acc = fmaf(w3, base[l], acc);
      if (l - 1 >= 0) acc = fmaf(w2, base[l - 1], acc);
      if (l - 2 >= 0) acc = fmaf(w1, base[l - 2], acc);
      if (l - 3 >= 0) acc = fmaf(w0, base[l - 3], acc);
    }
    xt[d][lc] = fsilu(acc);
  }
  __syncthreads();

  // x_dbl: 48 rows; thread handles r = rbase + 8i at fixed lc
  {
    const int rbase = tid >> 5;  // 0..7
    float accs[6] = {};
    for (int d = 0; d < DN; d++) {
      float xval = xt[d][lc];
#pragma unroll
      for (int i = 0; i < 6; i++)
        accs[i] = fmaf(x_w[(size_t)(rbase + i * 8) * DN + d], xval, accs[i]);
    }
#pragma unroll
    for (int i = 0; i < 6; i++) {
      int r = rbase + i * 8;
      if (r < 16)
        dtv[r][lc] = accs[i];
      else if (r < 32)
        Bc[((size_t)b * LL + l) * NS + (r - 16)] = accs[i];
      else
        Cc[((size_t)b * LL + l) * NS + (r - 32)] = accs[i];
    }
  }
  __syncthreads();

  // delta = softplus(dt @ dt_w^T + dt_b)
  {
    float dtl[RK];
#pragma unroll
    for (int r = 0; r < RK; r++) dtl[r] = dtv[r][lc];
#pragma unroll 4
    for (int i = 0; i < 64; i++) {
      int d = i * 8 + (tid >> 5);
      const float4* wrow = (const float4*)(dt_w + (size_t)d * RK);
      float4 wq0 = wrow[0], wq1 = wrow[1], wq2 = wrow[2], wq3 = wrow[3];
      float acc = dt_b[d];
      acc = fmaf(wq0.x, dtl[0], acc);  acc = fmaf(wq0.y, dtl[1], acc);
      acc = fmaf(wq0.z, dtl[2], acc);  acc = fmaf(wq0.w, dtl[3], acc);
      acc = fmaf(wq1.x, dtl[4], acc);  acc = fmaf(wq1.y, dtl[5], acc);
      acc = fmaf(wq1.z, dtl[6], acc);  acc = fmaf(wq1.w, dtl[7], acc);
      acc = fmaf(wq2.x, dtl[8], acc);  acc = fmaf(wq2.y, dtl[9], acc);
      acc = fmaf(wq2.z, dtl[10], acc); acc = fmaf(wq2.w, dtl[11], acc);
      acc = fmaf(wq3.x, dtl[12], acc); acc = fmaf(wq3.y, dtl[13], acc);
      acc = fmaf(wq3.z, dtl[14], acc); acc = fmaf(wq3.w, dtl[15], acc);
      delta_out[((size_t)b * DN + d) * LL + l] = fsoftplus(acc);
    }
  }
}

// ---------------------------------------------------------------------------
// selective scan: lane = state n, 16-lane group = one (branch,b,d) channel.
// Forward branch iterates t ascending; reverse branch t descending (so its
// output is written already flipped back). u recomputed via rolling 4-tap conv.
// ---------------------------------------------------------------------------
__global__ __launch_bounds__(256) void scan_kernel(
    const float* __restrict__ xz, const float* __restrict__ delta_f,
    const float* __restrict__ delta_r, const float* __restrict__ Bc_f,
    const float* __restrict__ Cc_f, const float* __restrict__ Bc_r,
    const float* __restrict__ Cc_r, const float* __restrict__ A_log,
    const float* __restrict__ Ab_log, const float* __restrict__ cw_f,
    const float* __restrict__ cb_f, const float* __restrict__ cw_r,
    const float* __restrict__ cb_r, const float* __restrict__ D_f,
    const float* __restrict__ D_r, float* __restrict__ y_f, float* __restrict__ y_r) {
  const int gid = blockIdx.x * 16 + (threadIdx.x >> 4);
  const int n = threadIdx.x & 15;
  const int rev = gid >= BB * DN;
  const int cid = rev ? gid - BB * DN : gid;
  const int b = cid / DN;
  const int d = cid % DN;

  const float Av = -__expf((rev ? Ab_log : A_log)[d * NS + n]);
  const float* cw = (rev ? cw_r : cw_f) + d * 4;
  const float w0 = cw[0], w1 = cw[1], w2 = cw[2], w3 = cw[3];
  const float cb = (rev ? cb_r : cb_f)[d];
  const float Dd = (rev ? D_r : D_f)[d];

  const float* xbase = xz + ((size_t)b * EE + d) * LL;
  const float* zbase = xz + ((size_t)b * EE + DN + d) * LL;
  const float* dbase = (rev ? delta_r : delta_f) + ((size_t)b * DN + d) * LL;
  const float* Bbase = (rev ? Bc_r : Bc_f) + (size_t)b * LL * NS + n;
  const float* Cbase = (rev ? Cc_r : Cc_f) + (size_t)b * LL * NS + n;
  float* ybase = (rev ? y_r : y_f) + ((size_t)b * DN + d) * LL;

  float h = 0.f, p1 = 0.f, p2 = 0.f, p3 = 0.f;
  int t = rev ? LL - 1 : 0;
  const int st = rev ? -1 : 1;
#pragma unroll 4
  for (int s = 0; s < LL; s++, t += st) {
    const float xin = xbase[t];
    const float dl = dbase[t];
    const float Bv = Bbase[(size_t)t * NS];
    const float Cv = Cbase[(size_t)t * NS];
    const float zv = zbase[t];
    float upre = w3 * xin + w2 * p1 + w1 * p2 + w0 * p3 + cb;
    p3 = p2; p2 = p1; p1 = xin;
    const float u = fsilu(upre);
    const float dA = __expf(dl * Av);
    h = dA * h + (dl * u) * Bv;
    float p = h * Cv;
    p += __shfl_xor(p, 1, 64);
    p += __shfl_xor(p, 2, 64);
    p += __shfl_xor(p, 4, 64);
    p += __shfl_xor(p, 8, 64);
    if (n == 0) ybase[t] = (p + u * Dd) * fsilu(zv);
  }
}

// ---------------------------------------------------------------------------
// out_proj: out[b][l][m] = sum_d ow[m][d] * 0.5*(yf+yr)[b][d][l]
// tile 64l x 128m, K-step 32, 256 threads, micro 4(l) x 8(m)
// ---------------------------------------------------------------------------
__global__ __launch_bounds__(256) void out_proj_kernel(
    const float* __restrict__ yf, const float* __restrict__ yr,
    const float* __restrict__ ow, float* __restrict__ outp) {
  __shared__ float ys[32][68];    // [k][l]
  __shared__ float wsm[32][132];  // [k][m]
  const int b = blockIdx.z;
  const int m0 = blockIdx.y * 128;
  const int l0 = blockIdx.x * 64;
  const int tid = threadIdx.x;
  const int tx = tid & 15;  // l
  const int ty = tid >> 4;  // m
  float acc[8][4] = {};
  for (int dk = 0; dk < DN; dk += 32) {
#pragma unroll
    for (int it = 0; it < 8; it++) {
      int idx = it * 256 + tid;
      int i = idx & 63;  // l (contiguous in y)
      int j = idx >> 6;  // k
      size_t yi = ((size_t)b * DN + dk + j) * LL + l0 + i;
      ys[j][i] = 0.5f * (yf[yi] + yr[yi]);
    }
#pragma unroll
    for (int it = 0; it < 16; it++) {
      int idx = it * 256 + tid;
      int j = idx & 31;  // k (contiguous in ow)
      int i = idx >> 5;  // m
      wsm[j][i] = ow[(size_t)(m0 + i) * DN + dk + j];
    }
    __syncthreads();
#pragma unroll
    for (int kk = 0; kk < 32; kk++) {
      const float4 y0 = *(const float4*)(&ys[kk][tx * 4]);
      const float4 w0 = *(const float4*)(&wsm[kk][ty * 8]);
      const float4 w1 = *(const float4*)(&wsm[kk][ty * 8 + 4]);
      const float yv[4] = {y0.x, y0.y, y0.z, y0.w};
      const float wv[8] = {w0.x, w0.y, w0.z, w0.w, w1.x, w1.y, w1.z, w1.w};
#pragma unroll
      for (int a = 0; a < 8; a++)
#pragma unroll
        for (int c = 0; c < 4; c++) acc[a][c] = fmaf(wv[a], yv[c], acc[a][c]);
    }
    __syncthreads();
  }
#pragma unroll
  for (int c = 0; c < 4; c++) {
    float* orow = outp + ((size_t)b * LL + l0 + tx * 4 + c) * DM + m0 + ty * 8;
    *(float4*)(orow) = make_float4(acc[0][c], acc[1][c], acc[2][c], acc[3][c]);
    *(float4*)(orow + 4) = make_float4(acc[4][c], acc[5][c], acc[6][c], acc[7][c]);
  }
}

// ---------------------------------------------------------------------------
extern "C" void kernel_launch(void* const* d_in, const int* in_sizes, int n_in,
                              void* d_out, int out_size, void* d_ws, size_t ws_size,
                              hipStream_t stream) {
  (void)in_sizes; (void)n_in; (void)out_size; (void)ws_size;
  const float* A_log = (const float*)d_in[2];
  const float* Ab_log = (const float*)d_in[3];

  float* ws = (float*)d_ws;
  float* xz = ws;                                      // BB*EE*LL
  float* delta_f = xz + (size_t)BB * EE * LL;          // BB*DN*LL
  float* delta_r = delta_f + (size_t)BB * DN * LL;     // BB*DN*LL
  float* Bc_f = delta_r + (size_t)BB * DN * LL;        // BB*LL*NS
  float* Cc_f = Bc_f + (size_t)BB * LL * NS;
  float* Bc_r = Cc_f + (size_t)BB * LL * NS;
  float* Cc_r = Bc_r + (size_t)BB * LL * NS;
  float* y_f = Cc_r + (size_t)BB * LL * NS;            // BB*DN*LL
  float* y_r = y_f + (size_t)BB * DN * LL;             // BB*DN*LL

  for (int s = 0; s < 2; s++) {
    const int p = 4 + s * 14;
    const float* hin = (const float*)d_in[s];
    const float* in_w = (const float*)d_in[p + 0];
    const float* conv_w = (const float*)d_in[p + 1];
    const float* conv_b = (const float*)d_in[p + 2];
    const float* x_w = (const float*)d_in[p + 3];
    const float* dt_w = (const float*)d_in[p + 4];
    const float* dt_b = (const float*)d_in[p + 5];
    const float* Dp = (const float*)d_in[p + 6];
    const float* conv_w_b = (const float*)d_in[p + 7];
    const float* conv_b_b = (const float*)d_in[p + 8];
    const float* x_w_b = (const float*)d_in[p + 9];
    const float* dt_w_b = (const float*)d_in[p + 10];
    const float* dt_b_b = (const float*)d_in[p + 11];
    const float* Dp_b = (const float*)d_in[p + 12];
    const float* out_w = (const float*)d_in[p + 13];
    float* outp = (float*)d_out + (size_t)s * BB * LL * DM;

    hipLaunchKernelGGL(in_proj_kernel, dim3(LL / 128, EE / 128, BB), dim3(256), 0,
                       stream, hin, in_w, xz);
    hipLaunchKernelGGL(HIP_KERNEL_NAME(convproj_kernel<0>), dim3(LL / 32, BB),
                       dim3(256), 0, stream, xz, conv_w, conv_b, x_w, dt_w, dt_b,
                       delta_f, Bc_f, Cc_f);
    hipLaunchKernelGGL(HIP_KERNEL_NAME(convproj_kernel<1>), dim3(LL / 32, BB),
                       dim3(256), 0, stream, xz, conv_w_b, conv_b_b, x_w_b, dt_w_b,
                       dt_b_b, delta_r, Bc_r, Cc_r);
    hipLaunchKernelGGL(scan_kernel, dim3(2 * BB * DN / 16), dim3(256), 0, stream, xz,
                       delta_f, delta_r, Bc_f, Cc_f, Bc_r, Cc_r, A_log, Ab_log,
                       conv_w, conv_b, conv_w_b, conv_b_b, Dp, Dp_b, y_f, y_r);
    hipLaunchKernelGGL(out_proj_kernel, dim3(LL / 64, DM / 128, BB), dim3(256), 0,
                       stream, y_f, y_r, out_w, outp);
  }
}

// Round 2
// 1315.742 us; speedup vs baseline: 1.9859x; 1.9859x over previous
//
#include <hip/hip_runtime.h>
#include <hip/hip_bf16.h>
#include <cstddef>

#define BB 4
#define LL 2048
#define DM 256
#define DN 512
#define EE 1024
#define NS 16
#define RK 16
#define NC 8           // scan chunks
#define CL (LL / NC)   // chunk length = 256

__device__ __forceinline__ float fsilu(float x) { return x / (1.0f + __expf(-x)); }
__device__ __forceinline__ float fsoftplus(float x) { return x > 20.0f ? x : log1pf(__expf(x)); }

// ---------------------------------------------------------------------------
// in_proj: xz[b][e][l] = sum_d in_w[e][d] * h[b][l][d]
// tile 128e x 128l, K-step 32, 256 threads, 8x8 microtile (lane-strided l/e
// reads from [row][k] pad-33 LDS: conflict-free reads AND writes)
// ---------------------------------------------------------------------------
__global__ __launch_bounds__(256) void in_proj_kernel(
    const float* __restrict__ h, const float* __restrict__ w, float* __restrict__ xz) {
  __shared__ float hs[128][33];   // [l][k]
  __shared__ float wsm[128][33];  // [e][k]
  const int b = blockIdx.z;
  const int e0 = blockIdx.y * 128;
  const int l0 = blockIdx.x * 128;
  const int tid = threadIdx.x;
  const int tx = tid & 15;  // l lane
  const int ty = tid >> 4;  // e group
  float acc[8][8] = {};     // [a(e)][c(l)]
  for (int dk = 0; dk < DM; dk += 32) {
#pragma unroll
    for (int it = 0; it < 16; it++) {
      int idx = it * 256 + tid;
      int i = idx >> 5;  // row (l or e)
      int j = idx & 31;  // k
      hs[i][j] = h[((size_t)b * LL + l0 + i) * DM + dk + j];
      wsm[i][j] = w[(size_t)(e0 + i) * DM + dk + j];
    }
    __syncthreads();
#pragma unroll
    for (int kk = 0; kk < 32; kk++) {
      float hv[8], wv[8];
#pragma unroll
      for (int c = 0; c < 8; c++) hv[c] = hs[tx + 16 * c][kk];
#pragma unroll
      for (int a = 0; a < 8; a++) wv[a] = wsm[ty * 8 + a][kk];
#pragma unroll
      for (int a = 0; a < 8; a++)
#pragma unroll
        for (int c = 0; c < 8; c++) acc[a][c] = fmaf(wv[a], hv[c], acc[a][c]);
    }
    __syncthreads();
  }
#pragma unroll
  for (int a = 0; a < 8; a++) {
#pragma unroll
    for (int c = 0; c < 8; c++)
      xz[((size_t)b * EE + e0 + ty * 8 + a) * LL + l0 + tx + 16 * c] = acc[a][c];
  }
}

// ---------------------------------------------------------------------------
// fused conv+silu -> x_dbl(48) -> delta(softplus). One block = (b, 32 l's).
// ---------------------------------------------------------------------------
template <int REV>
__global__ __launch_bounds__(256) void convproj_kernel(
    const float* __restrict__ xz, const float* __restrict__ conv_w,
    const float* __restrict__ conv_b, const float* __restrict__ x_w,
    const float* __restrict__ dt_w, const float* __restrict__ dt_b,
    float* __restrict__ delta_out, float* __restrict__ Bc, float* __restrict__ Cc) {
  __shared__ float xt[DN][32];
  __shared__ float dtv[RK][32];
  const int b = blockIdx.y;
  const int l0 = blockIdx.x * 32;
  const int tid = threadIdx.x;
  const int lc = tid & 31;
  const int l = l0 + lc;

#pragma unroll 4
  for (int i = 0; i < 64; i++) {
    int d = i * 8 + (tid >> 5);
    const float* base = xz + ((size_t)b * EE + d) * LL;
    float w0 = conv_w[d * 4 + 0], w1 = conv_w[d * 4 + 1];
    float w2 = conv_w[d * 4 + 2], w3 = conv_w[d * 4 + 3];
    float acc = conv_b[d];
    if (REV) {
      acc = fmaf(w3, base[l], acc);
      if (l + 1 < LL) acc = fmaf(w2, base[l + 1], acc);
      if (l + 2 < LL) acc = fmaf(w1, base[l + 2], acc);
      if (l + 3 < LL) acc = fmaf(w0, base[l + 3], acc);
    } else {
      acc = fmaf(w3, base[l], acc);
      if (l - 1 >= 0) acc = fmaf(w2, base[l - 1], acc);
      if (l - 2 >= 0) acc = fmaf(w1, base[l - 2], acc);
      if (l - 3 >= 0) acc = fmaf(w0, base[l - 3], acc);
    }
    xt[d][lc] = fsilu(acc);
  }
  __syncthreads();

  {
    const int rbase = tid >> 5;  // 0..7
    float accs[6] = {};
    for (int d = 0; d < DN; d++) {
      float xval = xt[d][lc];
#pragma unroll
      for (int i = 0; i < 6; i++)
        accs[i] = fmaf(x_w[(size_t)(rbase + i * 8) * DN + d], xval, accs[i]);
    }
#pragma unroll
    for (int i = 0; i < 6; i++) {
      int r = rbase + i * 8;
      if (r < 16)
        dtv[r][lc] = accs[i];
      else if (r < 32)
        Bc[((size_t)b * LL + l) * NS + (r - 16)] = accs[i];
      else
        Cc[((size_t)b * LL + l) * NS + (r - 32)] = accs[i];
    }
  }
  __syncthreads();

  {
    float dtl[RK];
#pragma unroll
    for (int r = 0; r < RK; r++) dtl[r] = dtv[r][lc];
#pragma unroll 4
    for (int i = 0; i < 64; i++) {
      int d = i * 8 + (tid >> 5);
      const float4* wrow = (const float4*)(dt_w + (size_t)d * RK);
      float4 wq0 = wrow[0], wq1 = wrow[1], wq2 = wrow[2], wq3 = wrow[3];
      float acc = dt_b[d];
      acc = fmaf(wq0.x, dtl[0], acc);  acc = fmaf(wq0.y, dtl[1], acc);
      acc = fmaf(wq0.z, dtl[2], acc);  acc = fmaf(wq0.w, dtl[3], acc);
      acc = fmaf(wq1.x, dtl[4], acc);  acc = fmaf(wq1.y, dtl[5], acc);
      acc = fmaf(wq1.z, dtl[6], acc);  acc = fmaf(wq1.w, dtl[7], acc);
      acc = fmaf(wq2.x, dtl[8], acc);  acc = fmaf(wq2.y, dtl[9], acc);
      acc = fmaf(wq2.z, dtl[10], acc); acc = fmaf(wq2.w, dtl[11], acc);
      acc = fmaf(wq3.x, dtl[12], acc); acc = fmaf(wq3.y, dtl[13], acc);
      acc = fmaf(wq3.z, dtl[14], acc); acc = fmaf(wq3.w, dtl[15], acc);
      delta_out[((size_t)b * DN + d) * LL + l] = fsoftplus(acc);
    }
  }
}

// ---------------------------------------------------------------------------
// Chunked selective scan. channel = (rev*BB + b)*DN + d  (G = 2*BB*DN = 4096)
// PHASE 1: per (channel,chunk): scan with h0=0, store hend[ch][c][n], sumdl.
// PHASE 3: per (channel,chunk): scan from h0[ch][c][n], write y.
// 16-lane group = one (channel,chunk); lane = state n.
// ---------------------------------------------------------------------------
template <int REV, int PHASE>
__device__ __forceinline__ void scan_chunk(
    const float* __restrict__ xbase, const float* __restrict__ zbase,
    const float* __restrict__ dbase, const float* __restrict__ Bbase,
    const float* __restrict__ Cbase, float Av, float w0, float w1, float w2,
    float w3, float cb, float Dd, int chunk, int n, int ch,
    float* __restrict__ hend, float* __restrict__ sumdl,
    const float* __restrict__ h0, float* __restrict__ ybase) {
  const int t0 = REV ? (LL - 1 - chunk * CL) : (chunk * CL);
  float p1 = 0.f, p2 = 0.f, p3 = 0.f;
  if (REV) {
    if (t0 + 1 < LL) { p1 = xbase[t0 + 1]; p2 = xbase[t0 + 2]; p3 = xbase[t0 + 3]; }
  } else {
    if (t0 - 1 >= 0) { p1 = xbase[t0 - 1]; p2 = xbase[t0 - 2]; p3 = xbase[t0 - 3]; }
  }
  float h = 0.f, sdl = 0.f;
  if (PHASE == 3) h = h0[((size_t)ch * NC + chunk) * NS + n];

  for (int kb = 0; kb < CL / 4; kb++) {
    const int tb = REV ? (t0 - kb * 4 - 3) : (t0 + kb * 4);
    const float4 x4 = *(const float4*)(xbase + tb);
    const float4 d4 = *(const float4*)(dbase + tb);
    float4 z4 = make_float4(0.f, 0.f, 0.f, 0.f);
    if (PHASE == 3) z4 = *(const float4*)(zbase + tb);
    const float xs[4] = {x4.x, x4.y, x4.z, x4.w};
    const float ds[4] = {d4.x, d4.y, d4.z, d4.w};
    const float zs[4] = {z4.x, z4.y, z4.z, z4.w};
#pragma unroll
    for (int j = 0; j < 4; j++) {
      const int jj = REV ? 3 - j : j;  // compile-time constant per unrolled j
      const float xin = xs[jj];
      const float dl = ds[jj];
      const int t = tb + jj;
      const float Bv = Bbase[(size_t)t * NS];
      const float upre = fmaf(w3, xin, fmaf(w2, p1, fmaf(w1, p2, fmaf(w0, p3, cb))));
      p3 = p2; p2 = p1; p1 = xin;
      const float u = fsilu(upre);
      const float dA = __expf(dl * Av);
      h = fmaf(dA, h, dl * u * Bv);
      if (PHASE == 1) sdl += dl;
      if (PHASE == 3) {
        const float Cv = Cbase[(size_t)t * NS];
        float p = h * Cv;
        p += __shfl_xor(p, 1, 64);
        p += __shfl_xor(p, 2, 64);
        p += __shfl_xor(p, 4, 64);
        p += __shfl_xor(p, 8, 64);
        if (n == 0) ybase[t] = (p + u * Dd) * fsilu(zs[jj]);
      }
    }
  }
  if (PHASE == 1) {
    hend[((size_t)ch * NC + chunk) * NS + n] = h;
    if (n == 0) sumdl[(size_t)ch * NC + chunk] = sdl;
  }
}

template <int PHASE>
__global__ __launch_bounds__(256) void scan_phase_kernel(
    const float* __restrict__ xz, const float* __restrict__ delta_f,
    const float* __restrict__ delta_r, const float* __restrict__ Bc_f,
    const float* __restrict__ Cc_f, const float* __restrict__ Bc_r,
    const float* __restrict__ Cc_r, const float* __restrict__ A_log,
    const float* __restrict__ Ab_log, const float* __restrict__ cw_f,
    const float* __restrict__ cb_f, const float* __restrict__ cw_r,
    const float* __restrict__ cb_r, const float* __restrict__ D_f,
    const float* __restrict__ D_r, float* __restrict__ hend,
    float* __restrict__ sumdl, const float* __restrict__ h0,
    float* __restrict__ y_f, float* __restrict__ y_r) {
  const int G = 2 * BB * DN;
  const int gidx = blockIdx.x * 16 + (threadIdx.x >> 4);
  const int n = threadIdx.x & 15;
  const int ch = gidx % G;      // adjacent groups = adjacent channels, same chunk
  const int chunk = gidx / G;
  const int rev = ch >= BB * DN;
  const int cid = rev ? ch - BB * DN : ch;
  const int b = cid / DN;
  const int d = cid % DN;

  const float Av = -__expf((rev ? Ab_log : A_log)[d * NS + n]);
  const float* cw = (rev ? cw_r : cw_f) + d * 4;
  const float w0 = cw[0], w1 = cw[1], w2 = cw[2], w3 = cw[3];
  const float cb = (rev ? cb_r : cb_f)[d];
  const float Dd = (rev ? D_r : D_f)[d];

  const float* xbase = xz + ((size_t)b * EE + d) * LL;
  const float* zbase = xz + ((size_t)b * EE + DN + d) * LL;
  const float* dbase = (rev ? delta_r : delta_f) + ((size_t)b * DN + d) * LL;
  const float* Bbase = (rev ? Bc_r : Bc_f) + (size_t)b * LL * NS + n;
  const float* Cbase = (rev ? Cc_r : Cc_f) + (size_t)b * LL * NS + n;
  float* ybase = (rev ? y_r : y_f) + ((size_t)b * DN + d) * LL;

  if (rev)
    scan_chunk<1, PHASE>(xbase, zbase, dbase, Bbase, Cbase, Av, w0, w1, w2, w3,
                         cb, Dd, chunk, n, ch, hend, sumdl, h0, ybase);
  else
    scan_chunk<0, PHASE>(xbase, zbase, dbase, Bbase, Cbase, Av, w0, w1, w2, w3,
                         cb, Dd, chunk, n, ch, hend, sumdl, h0, ybase);
}

// Phase 2: per (channel,n) combine chunk states: h0[c] = H_{c-1},
// H_c = exp(Av*sumdl[c]) * H_{c-1} + hend[c]
__global__ __launch_bounds__(256) void scan_combine_kernel(
    const float* __restrict__ A_log, const float* __restrict__ Ab_log,
    const float* __restrict__ hend, const float* __restrict__ sumdl,
    float* __restrict__ h0) {
  const int gtid = blockIdx.x * 256 + threadIdx.x;
  const int ch = gtid >> 4;
  const int n = gtid & 15;
  const int rev = ch >= BB * DN;
  const int d = ch % DN;
  const float Av = -__expf((rev ? Ab_log : A_log)[d * NS + n]);
  float H = 0.f;
#pragma unroll
  for (int c = 0; c < NC; c++) {
    h0[((size_t)ch * NC + c) * NS + n] = H;
    H = fmaf(__expf(Av * sumdl[(size_t)ch * NC + c]), H,
             hend[((size_t)ch * NC + c) * NS + n]);
  }
}

// ---------------------------------------------------------------------------
// out_proj: out[b][l][m] = sum_d ow[m][d] * 0.5*(yf+yr)[b][d][l]
// tile 128m x 64l, micro 8m x 4l; m on lane axis -> coalesced output stores
// ---------------------------------------------------------------------------
__global__ __launch_bounds__(256) void out_proj_kernel(
    const float* __restrict__ yf, const float* __restrict__ yr,
    const float* __restrict__ ow, float* __restrict__ outp) {
  __shared__ float ys[64][33];    // [l][k]
  __shared__ float wsm[128][33];  // [m][k]
  const int b = blockIdx.z;
  const int m0 = blockIdx.y * 128;
  const int l0 = blockIdx.x * 64;
  const int tid = threadIdx.x;
  const int tx = tid & 15;  // m lane
  const int ty = tid >> 4;  // l group
  float acc[8][4] = {};     // [cm][cl]
  for (int dk = 0; dk < DN; dk += 32) {
#pragma unroll
    for (int it = 0; it < 8; it++) {
      int idx = it * 256 + tid;
      int i = idx & 63;  // l (contiguous in y global)
      int j = idx >> 6;  // k
      size_t yi = ((size_t)b * DN + dk + j) * LL + l0 + i;
      ys[i][j] = 0.5f * (yf[yi] + yr[yi]);
    }
#pragma unroll
    for (int it = 0; it < 16; it++) {
      int idx = it * 256 + tid;
      int j = idx & 31;  // k (contiguous in ow)
      int i = idx >> 5;  // m
      wsm[i][j] = ow[(size_t)(m0 + i) * DN + dk + j];
    }
    __syncthreads();
#pragma unroll
    for (int kk = 0; kk < 32; kk++) {
      float wv[8], yv[4];
#pragma unroll
      for (int cm = 0; cm < 8; cm++) wv[cm] = wsm[tx + 16 * cm][kk];
#pragma unroll
      for (int cl = 0; cl < 4; cl++) yv[cl] = ys[ty * 4 + cl][kk];
#pragma unroll
      for (int cm = 0; cm < 8; cm++)
#pragma unroll
        for (int cl = 0; cl < 4; cl++) acc[cm][cl] = fmaf(wv[cm], yv[cl], acc[cm][cl]);
    }
    __syncthreads();
  }
#pragma unroll
  for (int cl = 0; cl < 4; cl++)
#pragma unroll
    for (int cm = 0; cm < 8; cm++)
      outp[((size_t)b * LL + l0 + ty * 4 + cl) * DM + m0 + tx + 16 * cm] = acc[cm][cl];
}

// ---------------------------------------------------------------------------
extern "C" void kernel_launch(void* const* d_in, const int* in_sizes, int n_in,
                              void* d_out, int out_size, void* d_ws, size_t ws_size,
                              hipStream_t stream) {
  (void)in_sizes; (void)n_in; (void)out_size; (void)ws_size;
  const float* A_log = (const float*)d_in[2];
  const float* Ab_log = (const float*)d_in[3];

  float* ws = (float*)d_ws;
  float* xz = ws;                                      // BB*EE*LL
  float* delta_f = xz + (size_t)BB * EE * LL;          // BB*DN*LL
  float* delta_r = delta_f + (size_t)BB * DN * LL;     // BB*DN*LL
  float* Bc_f = delta_r + (size_t)BB * DN * LL;        // BB*LL*NS
  float* Cc_f = Bc_f + (size_t)BB * LL * NS;
  float* Bc_r = Cc_f + (size_t)BB * LL * NS;
  float* Cc_r = Bc_r + (size_t)BB * LL * NS;
  float* y_f = Cc_r + (size_t)BB * LL * NS;            // BB*DN*LL
  float* y_r = y_f + (size_t)BB * DN * LL;             // BB*DN*LL
  float* hend = y_r + (size_t)BB * DN * LL;            // G*NC*NS = 524288
  float* h0 = hend + (size_t)2 * BB * DN * NC * NS;    // 524288
  float* sumdl = h0 + (size_t)2 * BB * DN * NC * NS;   // G*NC = 32768

  const int G = 2 * BB * DN;

  for (int s = 0; s < 2; s++) {
    const int p = 4 + s * 14;
    const float* hin = (const float*)d_in[s];
    const float* in_w = (const float*)d_in[p + 0];
    const float* conv_w = (const float*)d_in[p + 1];
    const float* conv_b = (const float*)d_in[p + 2];
    const float* x_w = (const float*)d_in[p + 3];
    const float* dt_w = (const float*)d_in[p + 4];
    const float* dt_b = (const float*)d_in[p + 5];
    const float* Dp = (const float*)d_in[p + 6];
    const float* conv_w_b = (const float*)d_in[p + 7];
    const float* conv_b_b = (const float*)d_in[p + 8];
    const float* x_w_b = (const float*)d_in[p + 9];
    const float* dt_w_b = (const float*)d_in[p + 10];
    const float* dt_b_b = (const float*)d_in[p + 11];
    const float* Dp_b = (const float*)d_in[p + 12];
    const float* out_w = (const float*)d_in[p + 13];
    float* outp = (float*)d_out + (size_t)s * BB * LL * DM;

    hipLaunchKernelGGL(in_proj_kernel, dim3(LL / 128, EE / 128, BB), dim3(256), 0,
                       stream, hin, in_w, xz);
    hipLaunchKernelGGL(HIP_KERNEL_NAME(convproj_kernel<0>), dim3(LL / 32, BB),
                       dim3(256), 0, stream, xz, conv_w, conv_b, x_w, dt_w, dt_b,
                       delta_f, Bc_f, Cc_f);
    hipLaunchKernelGGL(HIP_KERNEL_NAME(convproj_kernel<1>), dim3(LL / 32, BB),
                       dim3(256), 0, stream, xz, conv_w_b, conv_b_b, x_w_b, dt_w_b,
                       dt_b_b, delta_r, Bc_r, Cc_r);
    hipLaunchKernelGGL(HIP_KERNEL_NAME(scan_phase_kernel<1>), dim3(G * NC / 16),
                       dim3(256), 0, stream, xz, delta_f, delta_r, Bc_f, Cc_f, Bc_r,
                       Cc_r, A_log, Ab_log, conv_w, conv_b, conv_w_b, conv_b_b, Dp,
                       Dp_b, hend, sumdl, h0, y_f, y_r);
    hipLaunchKernelGGL(scan_combine_kernel, dim3(G * NS / 256), dim3(256), 0, stream,
                       A_log, Ab_log, hend, sumdl, h0);
    hipLaunchKernelGGL(HIP_KERNEL_NAME(scan_phase_kernel<3>), dim3(G * NC / 16),
                       dim3(256), 0, stream, xz, delta_f, delta_r, Bc_f, Cc_f, Bc_r,
                       Cc_r, A_log, Ab_log, conv_w, conv_b, conv_w_b, conv_b_b, Dp,
                       Dp_b, hend, sumdl, h0, y_f, y_r);
    hipLaunchKernelGGL(out_proj_kernel, dim3(LL / 64, DM / 128, BB), dim3(256), 0,
                       stream, y_f, y_r, out_w, outp);
  }
}

// Round 3
// 1275.888 us; speedup vs baseline: 2.0480x; 1.0312x over previous
//
#include <hip/hip_runtime.h>
#include <hip/hip_bf16.h>
#include <cstddef>

#define BB 4
#define LL 2048
#define DM 256
#define DN 512
#define EE 1024
#define NS 16
#define RK 16
#define NC 8           // scan chunks
#define CL (LL / NC)   // chunk length = 256

__device__ __forceinline__ float fsilu(float x) { return x / (1.0f + __expf(-x)); }
__device__ __forceinline__ float fsoftplus(float x) { return x > 20.0f ? x : log1pf(__expf(x)); }

// ---------------------------------------------------------------------------
// in_proj: xz[b][e][l] = sum_d in_w[e][d] * h[b][l][d]
// ---------------------------------------------------------------------------
__global__ __launch_bounds__(256) void in_proj_kernel(
    const float* __restrict__ h, const float* __restrict__ w, float* __restrict__ xz) {
  __shared__ float hs[128][33];   // [l][k]
  __shared__ float wsm[128][33];  // [e][k]
  const int b = blockIdx.z;
  const int e0 = blockIdx.y * 128;
  const int l0 = blockIdx.x * 128;
  const int tid = threadIdx.x;
  const int tx = tid & 15;  // l lane
  const int ty = tid >> 4;  // e group
  float acc[8][8] = {};     // [a(e)][c(l)]
  for (int dk = 0; dk < DM; dk += 32) {
#pragma unroll
    for (int it = 0; it < 16; it++) {
      int idx = it * 256 + tid;
      int i = idx >> 5;  // row (l or e)
      int j = idx & 31;  // k
      hs[i][j] = h[((size_t)b * LL + l0 + i) * DM + dk + j];
      wsm[i][j] = w[(size_t)(e0 + i) * DM + dk + j];
    }
    __syncthreads();
#pragma unroll
    for (int kk = 0; kk < 32; kk++) {
      float hv[8], wv[8];
#pragma unroll
      for (int c = 0; c < 8; c++) hv[c] = hs[tx + 16 * c][kk];
#pragma unroll
      for (int a = 0; a < 8; a++) wv[a] = wsm[ty * 8 + a][kk];
#pragma unroll
      for (int a = 0; a < 8; a++)
#pragma unroll
        for (int c = 0; c < 8; c++) acc[a][c] = fmaf(wv[a], hv[c], acc[a][c]);
    }
    __syncthreads();
  }
#pragma unroll
  for (int a = 0; a < 8; a++) {
#pragma unroll
    for (int c = 0; c < 8; c++)
      xz[((size_t)b * EE + e0 + ty * 8 + a) * LL + l0 + tx + 16 * c] = acc[a][c];
  }
}

// ---------------------------------------------------------------------------
// fused conv+silu -> store u -> x_dbl(48) -> delta(softplus)
// outputs: u[b][d][l], delta[b][d][l], Bt[b][n][l], Ct[b][n][l]
// REV==0 additionally rewrites the z-half of xz with silu(z) in place.
// ---------------------------------------------------------------------------
template <int REV>
__global__ __launch_bounds__(256) void convproj_kernel(
    float* __restrict__ xz, const float* __restrict__ conv_w,
    const float* __restrict__ conv_b, const float* __restrict__ x_w,
    const float* __restrict__ dt_w, const float* __restrict__ dt_b,
    float* __restrict__ u_out, float* __restrict__ delta_out,
    float* __restrict__ Bt, float* __restrict__ Ct) {
  __shared__ float xt[DN][32];
  __shared__ float dtv[RK][32];
  const int b = blockIdx.y;
  const int l0 = blockIdx.x * 32;
  const int tid = threadIdx.x;
  const int lc = tid & 31;
  const int l = l0 + lc;

  // conv + silu -> LDS + global u
#pragma unroll 4
  for (int i = 0; i < 64; i++) {
    int d = i * 8 + (tid >> 5);
    const float* base = xz + ((size_t)b * EE + d) * LL;
    float w0 = conv_w[d * 4 + 0], w1 = conv_w[d * 4 + 1];
    float w2 = conv_w[d * 4 + 2], w3 = conv_w[d * 4 + 3];
    float acc = conv_b[d];
    if (REV) {
      acc = fmaf(w3, base[l], acc);
      if (l + 1 < LL) acc = fmaf(w2, base[l + 1], acc);
      if (l + 2 < LL) acc = fmaf(w1, base[l + 2], acc);
      if (l + 3 < LL) acc = fmaf(w0, base[l + 3], acc);
    } else {
      acc = fmaf(w3, base[l], acc);
      if (l - 1 >= 0) acc = fmaf(w2, base[l - 1], acc);
      if (l - 2 >= 0) acc = fmaf(w1, base[l - 2], acc);
      if (l - 3 >= 0) acc = fmaf(w0, base[l - 3], acc);
    }
    float uv = fsilu(acc);
    xt[d][lc] = uv;
    u_out[((size_t)b * DN + d) * LL + l] = uv;
  }

  // z -> silu(z) in place (fwd kernel only; z is never read elsewhere)
  if (!REV) {
#pragma unroll 4
    for (int i = 0; i < 64; i++) {
      int d = i * 8 + (tid >> 5);
      float* zp = xz + ((size_t)b * EE + DN + d) * LL + l;
      *zp = fsilu(*zp);
    }
  }
  __syncthreads();

  // x_dbl: 48 rows
  {
    const int rbase = tid >> 5;  // 0..7
    float accs[6] = {};
    for (int d = 0; d < DN; d++) {
      float xval = xt[d][lc];
#pragma unroll
      for (int i = 0; i < 6; i++)
        accs[i] = fmaf(x_w[(size_t)(rbase + i * 8) * DN + d], xval, accs[i]);
    }
#pragma unroll
    for (int i = 0; i < 6; i++) {
      int r = rbase + i * 8;
      if (r < 16)
        dtv[r][lc] = accs[i];
      else if (r < 32)
        Bt[((size_t)b * NS + (r - 16)) * LL + l] = accs[i];
      else
        Ct[((size_t)b * NS + (r - 32)) * LL + l] = accs[i];
    }
  }
  __syncthreads();

  // delta = softplus(dt @ dt_w^T + dt_b)
  {
    float dtl[RK];
#pragma unroll
    for (int r = 0; r < RK; r++) dtl[r] = dtv[r][lc];
#pragma unroll 4
    for (int i = 0; i < 64; i++) {
      int d = i * 8 + (tid >> 5);
      const float4* wrow = (const float4*)(dt_w + (size_t)d * RK);
      float4 wq0 = wrow[0], wq1 = wrow[1], wq2 = wrow[2], wq3 = wrow[3];
      float acc = dt_b[d];
      acc = fmaf(wq0.x, dtl[0], acc);  acc = fmaf(wq0.y, dtl[1], acc);
      acc = fmaf(wq0.z, dtl[2], acc);  acc = fmaf(wq0.w, dtl[3], acc);
      acc = fmaf(wq1.x, dtl[4], acc);  acc = fmaf(wq1.y, dtl[5], acc);
      acc = fmaf(wq1.z, dtl[6], acc);  acc = fmaf(wq1.w, dtl[7], acc);
      acc = fmaf(wq2.x, dtl[8], acc);  acc = fmaf(wq2.y, dtl[9], acc);
      acc = fmaf(wq2.z, dtl[10], acc); acc = fmaf(wq2.w, dtl[11], acc);
      acc = fmaf(wq3.x, dtl[12], acc); acc = fmaf(wq3.y, dtl[13], acc);
      acc = fmaf(wq3.z, dtl[14], acc); acc = fmaf(wq3.w, dtl[15], acc);
      delta_out[((size_t)b * DN + d) * LL + l] = fsoftplus(acc);
    }
  }
}

// ---------------------------------------------------------------------------
// Chunked selective scan over precomputed u/delta/Bt/Ct/sz.
// channel = (rev*BB + b)*DN + d (G = 4096); 16-lane group = (channel,chunk),
// lane = state n. PHASE 1: store hend/sumdl (chunks 0..NC-2).
// PHASE 3: start from h0, write y over u.
// ---------------------------------------------------------------------------
template <int REV, int PHASE>
__device__ __forceinline__ void scan_chunk(
    float* uy, const float* __restrict__ dlb, const float* __restrict__ Btb,
    const float* __restrict__ Ctb, const float* __restrict__ szb, float Av,
    float Dd, int chunk, int n, int ch, float* __restrict__ hend,
    float* __restrict__ sumdl, const float* __restrict__ h0) {
  const int tlo = REV ? (LL - CL - chunk * CL) : (chunk * CL);
  float h = 0.f, sdl = 0.f;
  if (PHASE == 3) h = h0[((size_t)ch * NC + chunk) * NS + n];

  for (int kb = 0; kb < CL / 4; kb++) {
    const int tb = REV ? (tlo + CL - 4 - 4 * kb) : (tlo + 4 * kb);
    const float4 d4 = *(const float4*)(dlb + tb);
    const float4 u4 = *(const float4*)(uy + tb);
    const float4 B4 = *(const float4*)(Btb + tb);
    float4 C4 = make_float4(0.f, 0.f, 0.f, 0.f);
    float4 s4 = make_float4(0.f, 0.f, 0.f, 0.f);
    if (PHASE == 3) {
      C4 = *(const float4*)(Ctb + tb);
      s4 = *(const float4*)(szb + tb);
    }
    const float ds_[4] = {d4.x, d4.y, d4.z, d4.w};
    const float us_[4] = {u4.x, u4.y, u4.z, u4.w};
    const float Bs_[4] = {B4.x, B4.y, B4.z, B4.w};
    const float Cs_[4] = {C4.x, C4.y, C4.z, C4.w};
    const float ss_[4] = {s4.x, s4.y, s4.z, s4.w};
#pragma unroll
    for (int j = 0; j < 4; j++) {
      const int jj = REV ? 3 - j : j;
      const float dl = ds_[jj];
      const float uu = us_[jj];
      const float dA = __expf(dl * Av);
      h = fmaf(dA, h, dl * uu * Bs_[jj]);
      if (PHASE == 1) sdl += dl;
      if (PHASE == 3) {
        float p = h * Cs_[jj];
        p += __shfl_xor(p, 1, 64);
        p += __shfl_xor(p, 2, 64);
        p += __shfl_xor(p, 4, 64);
        p += __shfl_xor(p, 8, 64);
        if (n == 0) uy[tb + jj] = fmaf(uu, Dd, p) * ss_[jj];
      }
    }
  }
  if (PHASE == 1) {
    hend[((size_t)ch * NC + chunk) * NS + n] = h;
    if (n == 0) sumdl[(size_t)ch * NC + chunk] = sdl;
  }
}

template <int PHASE>
__global__ __launch_bounds__(256) void scan_phase_kernel(
    const float* __restrict__ xz,  // z-half holds silu(z)
    float* uy_f, float* uy_r, const float* __restrict__ dl_f,
    const float* __restrict__ dl_r, const float* __restrict__ Bt_f,
    const float* __restrict__ Ct_f, const float* __restrict__ Bt_r,
    const float* __restrict__ Ct_r, const float* __restrict__ A_log,
    const float* __restrict__ Ab_log, const float* __restrict__ D_f,
    const float* __restrict__ D_r, float* __restrict__ hend,
    float* __restrict__ sumdl, const float* __restrict__ h0) {
  const int G = 2 * BB * DN;
  const int gidx = blockIdx.x * 16 + (threadIdx.x >> 4);
  const int n = threadIdx.x & 15;
  const int ch = gidx % G;
  const int chunk = gidx / G;
  const int rev = ch >= BB * DN;
  const int cid = rev ? ch - BB * DN : ch;
  const int b = cid / DN;
  const int d = cid % DN;

  const float Av = -__expf((rev ? Ab_log : A_log)[d * NS + n]);
  const float Dd = (rev ? D_r : D_f)[d];

  float* uy = (rev ? uy_r : uy_f) + ((size_t)b * DN + d) * LL;
  const float* dlb = (rev ? dl_r : dl_f) + ((size_t)b * DN + d) * LL;
  const float* Btb = (rev ? Bt_r : Bt_f) + ((size_t)b * NS + n) * LL;
  const float* Ctb = (rev ? Ct_r : Ct_f) + ((size_t)b * NS + n) * LL;
  const float* szb = xz + ((size_t)b * EE + DN + d) * LL;

  if (rev)
    scan_chunk<1, PHASE>(uy, dlb, Btb, Ctb, szb, Av, Dd, chunk, n, ch, hend,
                         sumdl, h0);
  else
    scan_chunk<0, PHASE>(uy, dlb, Btb, Ctb, szb, Av, Dd, chunk, n, ch, hend,
                         sumdl, h0);
}

// Phase 2: per (channel,n): h0[c] = H_{c-1}; H_c = exp(Av*sumdl[c])*H_{c-1} + hend[c]
__global__ __launch_bounds__(256) void scan_combine_kernel(
    const float* __restrict__ A_log, const float* __restrict__ Ab_log,
    const float* __restrict__ hend, const float* __restrict__ sumdl,
    float* __restrict__ h0) {
  const int gtid = blockIdx.x * 256 + threadIdx.x;
  const int ch = gtid >> 4;
  const int n = gtid & 15;
  const int rev = ch >= BB * DN;
  const int d = ch % DN;
  const float Av = -__expf((rev ? Ab_log : A_log)[d * NS + n]);
  float H = 0.f;
#pragma unroll
  for (int c = 0; c < NC; c++) {
    h0[((size_t)ch * NC + c) * NS + n] = H;
    if (c < NC - 1)
      H = fmaf(__expf(Av * sumdl[(size_t)ch * NC + c]), H,
               hend[((size_t)ch * NC + c) * NS + n]);
  }
}

// ---------------------------------------------------------------------------
// out_proj: out[b][l][m] = sum_d ow[m][d] * 0.5*(yf+yr)[b][d][l]
// ---------------------------------------------------------------------------
__global__ __launch_bounds__(256) void out_proj_kernel(
    const float* __restrict__ yf, const float* __restrict__ yr,
    const float* __restrict__ ow, float* __restrict__ outp) {
  __shared__ float ys[64][33];    // [l][k]
  __shared__ float wsm[128][33];  // [m][k]
  const int b = blockIdx.z;
  const int m0 = blockIdx.y * 128;
  const int l0 = blockIdx.x * 64;
  const int tid = threadIdx.x;
  const int tx = tid & 15;  // m lane
  const int ty = tid >> 4;  // l group
  float acc[8][4] = {};     // [cm][cl]
  for (int dk = 0; dk < DN; dk += 32) {
#pragma unroll
    for (int it = 0; it < 8; it++) {
      int idx = it * 256 + tid;
      int i = idx & 63;  // l
      int j = idx >> 6;  // k
      size_t yi = ((size_t)b * DN + dk + j) * LL + l0 + i;
      ys[i][j] = 0.5f * (yf[yi] + yr[yi]);
    }
#pragma unroll
    for (int it = 0; it < 16; it++) {
      int idx = it * 256 + tid;
      int j = idx & 31;  // k
      int i = idx >> 5;  // m
      wsm[i][j] = ow[(size_t)(m0 + i) * DN + dk + j];
    }
    __syncthreads();
#pragma unroll
    for (int kk = 0; kk < 32; kk++) {
      float wv[8], yv[4];
#pragma unroll
      for (int cm = 0; cm < 8; cm++) wv[cm] = wsm[tx + 16 * cm][kk];
#pragma unroll
      for (int cl = 0; cl < 4; cl++) yv[cl] = ys[ty * 4 + cl][kk];
#pragma unroll
      for (int cm = 0; cm < 8; cm++)
#pragma unroll
        for (int cl = 0; cl < 4; cl++) acc[cm][cl] = fmaf(wv[cm], yv[cl], acc[cm][cl]);
    }
    __syncthreads();
  }
#pragma unroll
  for (int cl = 0; cl < 4; cl++)
#pragma unroll
    for (int cm = 0; cm < 8; cm++)
      outp[((size_t)b * LL + l0 + ty * 4 + cl) * DM + m0 + tx + 16 * cm] = acc[cm][cl];
}

// ---------------------------------------------------------------------------
extern "C" void kernel_launch(void* const* d_in, const int* in_sizes, int n_in,
                              void* d_out, int out_size, void* d_ws, size_t ws_size,
                              hipStream_t stream) {
  (void)in_sizes; (void)n_in; (void)out_size; (void)ws_size;
  const float* A_log = (const float*)d_in[2];
  const float* Ab_log = (const float*)d_in[3];

  float* ws = (float*)d_ws;
  float* xz = ws;                                      // BB*EE*LL      (32 MB)
  float* uy_f = xz + (size_t)BB * EE * LL;             // BB*DN*LL  u -> y (fwd)
  float* uy_r = uy_f + (size_t)BB * DN * LL;           // BB*DN*LL  u -> y (rev)
  float* dl_f = uy_r + (size_t)BB * DN * LL;           // BB*DN*LL
  float* dl_r = dl_f + (size_t)BB * DN * LL;           // BB*DN*LL
  float* Bt_f = dl_r + (size_t)BB * DN * LL;           // BB*NS*LL
  float* Ct_f = Bt_f + (size_t)BB * NS * LL;
  float* Bt_r = Ct_f + (size_t)BB * NS * LL;
  float* Ct_r = Bt_r + (size_t)BB * NS * LL;
  float* hend = Ct_r + (size_t)BB * NS * LL;           // G*NC*NS
  float* h0 = hend + (size_t)2 * BB * DN * NC * NS;    // G*NC*NS
  float* sumdl = h0 + (size_t)2 * BB * DN * NC * NS;   // G*NC

  const int G = 2 * BB * DN;

  for (int s = 0; s < 2; s++) {
    const int p = 4 + s * 14;
    const float* hin = (const float*)d_in[s];
    const float* in_w = (const float*)d_in[p + 0];
    const float* conv_w = (const float*)d_in[p + 1];
    const float* conv_b = (const float*)d_in[p + 2];
    const float* x_w = (const float*)d_in[p + 3];
    const float* dt_w = (const float*)d_in[p + 4];
    const float* dt_b = (const float*)d_in[p + 5];
    const float* Dp = (const float*)d_in[p + 6];
    const float* conv_w_b = (const float*)d_in[p + 7];
    const float* conv_b_b = (const float*)d_in[p + 8];
    const float* x_w_b = (const float*)d_in[p + 9];
    const float* dt_w_b = (const float*)d_in[p + 10];
    const float* dt_b_b = (const float*)d_in[p + 11];
    const float* Dp_b = (const float*)d_in[p + 12];
    const float* out_w = (const float*)d_in[p + 13];
    float* outp = (float*)d_out + (size_t)s * BB * LL * DM;

    hipLaunchKernelGGL(in_proj_kernel, dim3(LL / 128, EE / 128, BB), dim3(256), 0,
                       stream, hin, in_w, xz);
    hipLaunchKernelGGL(HIP_KERNEL_NAME(convproj_kernel<0>), dim3(LL / 32, BB),
                       dim3(256), 0, stream, xz, conv_w, conv_b, x_w, dt_w, dt_b,
                       uy_f, dl_f, Bt_f, Ct_f);
    hipLaunchKernelGGL(HIP_KERNEL_NAME(convproj_kernel<1>), dim3(LL / 32, BB),
                       dim3(256), 0, stream, xz, conv_w_b, conv_b_b, x_w_b, dt_w_b,
                       dt_b_b, uy_r, dl_r, Bt_r, Ct_r);
    hipLaunchKernelGGL(HIP_KERNEL_NAME(scan_phase_kernel<1>),
                       dim3((NC - 1) * G / 16), dim3(256), 0, stream, xz, uy_f,
                       uy_r, dl_f, dl_r, Bt_f, Ct_f, Bt_r, Ct_r, A_log, Ab_log, Dp,
                       Dp_b, hend, sumdl, h0);
    hipLaunchKernelGGL(scan_combine_kernel, dim3(G * NS / 256), dim3(256), 0, stream,
                       A_log, Ab_log, hend, sumdl, h0);
    hipLaunchKernelGGL(HIP_KERNEL_NAME(scan_phase_kernel<3>), dim3(NC * G / 16),
                       dim3(256), 0, stream, xz, uy_f, uy_r, dl_f, dl_r, Bt_f, Ct_f,
                       Bt_r, Ct_r, A_log, Ab_log, Dp, Dp_b, hend, sumdl, h0);
    hipLaunchKernelGGL(out_proj_kernel, dim3(LL / 64, DM / 128, BB), dim3(256), 0,
                       stream, uy_f, uy_r, out_w, outp);
  }
}

// Round 4
// 1225.271 us; speedup vs baseline: 2.1326x; 1.0413x over previous
//
#include <hip/hip_runtime.h>
#include <hip/hip_bf16.h>
#include <cstddef>

#define BB 4
#define LL 2048
#define DM 256
#define DN 512
#define EE 1024
#define NS 16
#define RK 16
#define NC 8           // scan chunks
#define CL (LL / NC)   // chunk length = 256

__device__ __forceinline__ float fsilu(float x) { return x / (1.0f + __expf(-x)); }
__device__ __forceinline__ float fsoftplus(float x) { return x > 20.0f ? x : log1pf(__expf(x)); }

// ---------------------------------------------------------------------------
// in_proj: xz[b][e][l] = sum_d in_w[e][d] * h[b][l][d]
// ---------------------------------------------------------------------------
__global__ __launch_bounds__(256) void in_proj_kernel(
    const float* __restrict__ h, const float* __restrict__ w, float* __restrict__ xz) {
  __shared__ float hs[128][33];   // [l][k]
  __shared__ float wsm[128][33];  // [e][k]
  const int b = blockIdx.z;
  const int e0 = blockIdx.y * 128;
  const int l0 = blockIdx.x * 128;
  const int tid = threadIdx.x;
  const int tx = tid & 15;  // l lane
  const int ty = tid >> 4;  // e group
  float acc[8][8] = {};     // [a(e)][c(l)]
  for (int dk = 0; dk < DM; dk += 32) {
#pragma unroll
    for (int it = 0; it < 16; it++) {
      int idx = it * 256 + tid;
      int i = idx >> 5;  // row (l or e)
      int j = idx & 31;  // k
      hs[i][j] = h[((size_t)b * LL + l0 + i) * DM + dk + j];
      wsm[i][j] = w[(size_t)(e0 + i) * DM + dk + j];
    }
    __syncthreads();
#pragma unroll
    for (int kk = 0; kk < 32; kk++) {
      float hv[8], wv[8];
#pragma unroll
      for (int c = 0; c < 8; c++) hv[c] = hs[tx + 16 * c][kk];
#pragma unroll
      for (int a = 0; a < 8; a++) wv[a] = wsm[ty * 8 + a][kk];
#pragma unroll
      for (int a = 0; a < 8; a++)
#pragma unroll
        for (int c = 0; c < 8; c++) acc[a][c] = fmaf(wv[a], hv[c], acc[a][c]);
    }
    __syncthreads();
  }
#pragma unroll
  for (int a = 0; a < 8; a++) {
#pragma unroll
    for (int c = 0; c < 8; c++)
      xz[((size_t)b * EE + e0 + ty * 8 + a) * LL + l0 + tx + 16 * c] = acc[a][c];
  }
}

// ---------------------------------------------------------------------------
// fused conv+silu -> store u -> x_dbl(48) -> delta(softplus)
// outputs: u[b][d][l], delta[b][d][l], Bt[b][n][l], Ct[b][n][l]
// REV==0 additionally rewrites the z-half of xz with silu(z) in place.
// ---------------------------------------------------------------------------
template <int REV>
__global__ __launch_bounds__(256) void convproj_kernel(
    float* __restrict__ xz, const float* __restrict__ conv_w,
    const float* __restrict__ conv_b, const float* __restrict__ x_w,
    const float* __restrict__ dt_w, const float* __restrict__ dt_b,
    float* __restrict__ u_out, float* __restrict__ delta_out,
    float* __restrict__ Bt, float* __restrict__ Ct) {
  __shared__ float xt[DN][32];
  __shared__ float dtv[RK][32];
  const int b = blockIdx.y;
  const int l0 = blockIdx.x * 32;
  const int tid = threadIdx.x;
  const int lc = tid & 31;
  const int l = l0 + lc;

  // conv + silu -> LDS + global u
#pragma unroll 4
  for (int i = 0; i < 64; i++) {
    int d = i * 8 + (tid >> 5);
    const float* base = xz + ((size_t)b * EE + d) * LL;
    float w0 = conv_w[d * 4 + 0], w1 = conv_w[d * 4 + 1];
    float w2 = conv_w[d * 4 + 2], w3 = conv_w[d * 4 + 3];
    float acc = conv_b[d];
    if (REV) {
      acc = fmaf(w3, base[l], acc);
      if (l + 1 < LL) acc = fmaf(w2, base[l + 1], acc);
      if (l + 2 < LL) acc = fmaf(w1, base[l + 2], acc);
      if (l + 3 < LL) acc = fmaf(w0, base[l + 3], acc);
    } else {
      acc = fmaf(w3, base[l], acc);
      if (l - 1 >= 0) acc = fmaf(w2, base[l - 1], acc);
      if (l - 2 >= 0) acc = fmaf(w1, base[l - 2], acc);
      if (l - 3 >= 0) acc = fmaf(w0, base[l - 3], acc);
    }
    float uv = fsilu(acc);
    xt[d][lc] = uv;
    u_out[((size_t)b * DN + d) * LL + l] = uv;
  }

  // z -> silu(z) in place (fwd kernel only; z is never read elsewhere)
  if (!REV) {
#pragma unroll 4
    for (int i = 0; i < 64; i++) {
      int d = i * 8 + (tid >> 5);
      float* zp = xz + ((size_t)b * EE + DN + d) * LL + l;
      *zp = fsilu(*zp);
    }
  }
  __syncthreads();

  // x_dbl: 48 rows
  {
    const int rbase = tid >> 5;  // 0..7
    float accs[6] = {};
    for (int d = 0; d < DN; d++) {
      float xval = xt[d][lc];
#pragma unroll
      for (int i = 0; i < 6; i++)
        accs[i] = fmaf(x_w[(size_t)(rbase + i * 8) * DN + d], xval, accs[i]);
    }
#pragma unroll
    for (int i = 0; i < 6; i++) {
      int r = rbase + i * 8;
      if (r < 16)
        dtv[r][lc] = accs[i];
      else if (r < 32)
        Bt[((size_t)b * NS + (r - 16)) * LL + l] = accs[i];
      else
        Ct[((size_t)b * NS + (r - 32)) * LL + l] = accs[i];
    }
  }
  __syncthreads();

  // delta = softplus(dt @ dt_w^T + dt_b)
  {
    float dtl[RK];
#pragma unroll
    for (int r = 0; r < RK; r++) dtl[r] = dtv[r][lc];
#pragma unroll 4
    for (int i = 0; i < 64; i++) {
      int d = i * 8 + (tid >> 5);
      const float4* wrow = (const float4*)(dt_w + (size_t)d * RK);
      float4 wq0 = wrow[0], wq1 = wrow[1], wq2 = wrow[2], wq3 = wrow[3];
      float acc = dt_b[d];
      acc = fmaf(wq0.x, dtl[0], acc);  acc = fmaf(wq0.y, dtl[1], acc);
      acc = fmaf(wq0.z, dtl[2], acc);  acc = fmaf(wq0.w, dtl[3], acc);
      acc = fmaf(wq1.x, dtl[4], acc);  acc = fmaf(wq1.y, dtl[5], acc);
      acc = fmaf(wq1.z, dtl[6], acc);  acc = fmaf(wq1.w, dtl[7], acc);
      acc = fmaf(wq2.x, dtl[8], acc);  acc = fmaf(wq2.y, dtl[9], acc);
      acc = fmaf(wq2.z, dtl[10], acc); acc = fmaf(wq2.w, dtl[11], acc);
      acc = fmaf(wq3.x, dtl[12], acc); acc = fmaf(wq3.y, dtl[13], acc);
      acc = fmaf(wq3.z, dtl[14], acc); acc = fmaf(wq3.w, dtl[15], acc);
      delta_out[((size_t)b * DN + d) * LL + l] = fsoftplus(acc);
    }
  }
}

// ---------------------------------------------------------------------------
// Chunked selective scan. NO local arrays (scratch-spill hazard) — explicit
// .x/.y/.z/.w component access, direction via compile-time REV ordering.
// PHASE 1: store hend/sumdl. PHASE 3: start from h0, write y (separate buf).
// ---------------------------------------------------------------------------
template <int REV, int PHASE>
__device__ __forceinline__ void scan_chunk(
    const float* __restrict__ ub, float* __restrict__ yb,
    const float* __restrict__ dlb, const float* __restrict__ Btb,
    const float* __restrict__ Ctb, const float* __restrict__ szb, float Av,
    float Dd, int chunk, int n, int ch, float* __restrict__ hend,
    float* __restrict__ sumdl, const float* __restrict__ h0) {
  const int tlo = REV ? (LL - CL - chunk * CL) : (chunk * CL);
  float h = 0.f, sdl = 0.f;
  if (PHASE == 3) h = h0[((size_t)ch * NC + chunk) * NS + n];

  for (int kb = 0; kb < CL / 4; kb++) {
    const int tb = REV ? (tlo + CL - 4 - 4 * kb) : (tlo + 4 * kb);
    const float4 d4 = *(const float4*)(dlb + tb);
    const float4 u4 = *(const float4*)(ub + tb);
    const float4 B4 = *(const float4*)(Btb + tb);
    float4 C4 = make_float4(0.f, 0.f, 0.f, 0.f);
    float4 s4 = make_float4(0.f, 0.f, 0.f, 0.f);
    if (PHASE == 3) {
      C4 = *(const float4*)(Ctb + tb);
      s4 = *(const float4*)(szb + tb);
    }
    const float e0 = __expf(d4.x * Av);
    const float e1 = __expf(d4.y * Av);
    const float e2 = __expf(d4.z * Av);
    const float e3 = __expf(d4.w * Av);
    float p0, p1, p2, p3;
    if (REV) {
      h = fmaf(e3, h, d4.w * u4.w * B4.w); p3 = h * C4.w;
      h = fmaf(e2, h, d4.z * u4.z * B4.z); p2 = h * C4.z;
      h = fmaf(e1, h, d4.y * u4.y * B4.y); p1 = h * C4.y;
      h = fmaf(e0, h, d4.x * u4.x * B4.x); p0 = h * C4.x;
    } else {
      h = fmaf(e0, h, d4.x * u4.x * B4.x); p0 = h * C4.x;
      h = fmaf(e1, h, d4.y * u4.y * B4.y); p1 = h * C4.y;
      h = fmaf(e2, h, d4.z * u4.z * B4.z); p2 = h * C4.z;
      h = fmaf(e3, h, d4.w * u4.w * B4.w); p3 = h * C4.w;
    }
    if (PHASE == 1) sdl += (d4.x + d4.y) + (d4.z + d4.w);
    if (PHASE == 3) {
      // 4 independent shfl-xor reduction trees, interleaved for ILP
      p0 += __shfl_xor(p0, 1, 64); p1 += __shfl_xor(p1, 1, 64);
      p2 += __shfl_xor(p2, 1, 64); p3 += __shfl_xor(p3, 1, 64);
      p0 += __shfl_xor(p0, 2, 64); p1 += __shfl_xor(p1, 2, 64);
      p2 += __shfl_xor(p2, 2, 64); p3 += __shfl_xor(p3, 2, 64);
      p0 += __shfl_xor(p0, 4, 64); p1 += __shfl_xor(p1, 4, 64);
      p2 += __shfl_xor(p2, 4, 64); p3 += __shfl_xor(p3, 4, 64);
      p0 += __shfl_xor(p0, 8, 64); p1 += __shfl_xor(p1, 8, 64);
      p2 += __shfl_xor(p2, 8, 64); p3 += __shfl_xor(p3, 8, 64);
      if (n == 0) {
        float4 yv;
        yv.x = fmaf(u4.x, Dd, p0) * s4.x;
        yv.y = fmaf(u4.y, Dd, p1) * s4.y;
        yv.z = fmaf(u4.z, Dd, p2) * s4.z;
        yv.w = fmaf(u4.w, Dd, p3) * s4.w;
        *(float4*)(yb + tb) = yv;
      }
    }
  }
  if (PHASE == 1) {
    hend[((size_t)ch * NC + chunk) * NS + n] = h;
    if (n == 0) sumdl[(size_t)ch * NC + chunk] = sdl;
  }
}

template <int PHASE>
__global__ __launch_bounds__(256) void scan_phase_kernel(
    const float* __restrict__ xz,  // z-half holds silu(z)
    const float* __restrict__ u_f, const float* __restrict__ u_r,
    float* __restrict__ y_f,  // strided: row (b,d) at (b*EE + d)*LL
    float* __restrict__ y_r,  // row (b,d) at (b*DN + d)*LL
    const float* __restrict__ dl_f, const float* __restrict__ dl_r,
    const float* __restrict__ Bt_f, const float* __restrict__ Ct_f,
    const float* __restrict__ Bt_r, const float* __restrict__ Ct_r,
    const float* __restrict__ A_log, const float* __restrict__ Ab_log,
    const float* __restrict__ D_f, const float* __restrict__ D_r,
    float* __restrict__ hend, float* __restrict__ sumdl,
    const float* __restrict__ h0) {
  const int G = 2 * BB * DN;
  const int gidx = blockIdx.x * 16 + (threadIdx.x >> 4);
  const int n = threadIdx.x & 15;
  const int ch = gidx % G;
  const int chunk = gidx / G;
  const int rev = ch >= BB * DN;
  const int cid = rev ? ch - BB * DN : ch;
  const int b = cid / DN;
  const int d = cid % DN;

  const float Av = -__expf((rev ? Ab_log : A_log)[d * NS + n]);
  const float Dd = (rev ? D_r : D_f)[d];

  const float* ub = (rev ? u_r : u_f) + ((size_t)b * DN + d) * LL;
  float* yb = rev ? (y_r + ((size_t)b * DN + d) * LL)
                  : (y_f + ((size_t)b * EE + d) * LL);
  const float* dlb = (rev ? dl_r : dl_f) + ((size_t)b * DN + d) * LL;
  const float* Btb = (rev ? Bt_r : Bt_f) + ((size_t)b * NS + n) * LL;
  const float* Ctb = (rev ? Ct_r : Ct_f) + ((size_t)b * NS + n) * LL;
  const float* szb = xz + ((size_t)b * EE + DN + d) * LL;

  if (rev)
    scan_chunk<1, PHASE>(ub, yb, dlb, Btb, Ctb, szb, Av, Dd, chunk, n, ch,
                         hend, sumdl, h0);
  else
    scan_chunk<0, PHASE>(ub, yb, dlb, Btb, Ctb, szb, Av, Dd, chunk, n, ch,
                         hend, sumdl, h0);
}

// Phase 2: per (channel,n): h0[c] = H_{c-1}; H_c = exp(Av*sumdl[c])*H_{c-1} + hend[c]
__global__ __launch_bounds__(256) void scan_combine_kernel(
    const float* __restrict__ A_log, const float* __restrict__ Ab_log,
    const float* __restrict__ hend, const float* __restrict__ sumdl,
    float* __restrict__ h0) {
  const int gtid = blockIdx.x * 256 + threadIdx.x;
  const int ch = gtid >> 4;
  const int n = gtid & 15;
  const int rev = ch >= BB * DN;
  const int d = ch % DN;
  const float Av = -__expf((rev ? Ab_log : A_log)[d * NS + n]);
  float H = 0.f;
#pragma unroll
  for (int c = 0; c < NC; c++) {
    h0[((size_t)ch * NC + c) * NS + n] = H;
    if (c < NC - 1)
      H = fmaf(__expf(Av * sumdl[(size_t)ch * NC + c]), H,
               hend[((size_t)ch * NC + c) * NS + n]);
  }
}

// ---------------------------------------------------------------------------
// out_proj: out[b][l][m] = sum_d ow[m][d] * 0.5*(yf+yr)[b][d][l]
// yf rows at (b*EE+d)*LL (aliased into xz x-half); yr rows at (b*DN+d)*LL
// ---------------------------------------------------------------------------
__global__ __launch_bounds__(256) void out_proj_kernel(
    const float* __restrict__ yf, const float* __restrict__ yr,
    const float* __restrict__ ow, float* __restrict__ outp) {
  __shared__ float ys[64][33];    // [l][k]
  __shared__ float wsm[128][33];  // [m][k]
  const int b = blockIdx.z;
  const int m0 = blockIdx.y * 128;
  const int l0 = blockIdx.x * 64;
  const int tid = threadIdx.x;
  const int tx = tid & 15;  // m lane
  const int ty = tid >> 4;  // l group
  float acc[8][4] = {};     // [cm][cl]
  for (int dk = 0; dk < DN; dk += 32) {
#pragma unroll
    for (int it = 0; it < 8; it++) {
      int idx = it * 256 + tid;
      int i = idx & 63;  // l
      int j = idx >> 6;  // k
      float fv = yf[((size_t)b * EE + dk + j) * LL + l0 + i];
      float rv = yr[((size_t)b * DN + dk + j) * LL + l0 + i];
      ys[i][j] = 0.5f * (fv + rv);
    }
#pragma unroll
    for (int it = 0; it < 16; it++) {
      int idx = it * 256 + tid;
      int j = idx & 31;  // k
      int i = idx >> 5;  // m
      wsm[i][j] = ow[(size_t)(m0 + i) * DN + dk + j];
    }
    __syncthreads();
#pragma unroll
    for (int kk = 0; kk < 32; kk++) {
      float wv[8], yv[4];
#pragma unroll
      for (int cm = 0; cm < 8; cm++) wv[cm] = wsm[tx + 16 * cm][kk];
#pragma unroll
      for (int cl = 0; cl < 4; cl++) yv[cl] = ys[ty * 4 + cl][kk];
#pragma unroll
      for (int cm = 0; cm < 8; cm++)
#pragma unroll
        for (int cl = 0; cl < 4; cl++) acc[cm][cl] = fmaf(wv[cm], yv[cl], acc[cm][cl]);
    }
    __syncthreads();
  }
#pragma unroll
  for (int cl = 0; cl < 4; cl++)
#pragma unroll
    for (int cm = 0; cm < 8; cm++)
      outp[((size_t)b * LL + l0 + ty * 4 + cl) * DM + m0 + tx + 16 * cm] = acc[cm][cl];
}

// ---------------------------------------------------------------------------
extern "C" void kernel_launch(void* const* d_in, const int* in_sizes, int n_in,
                              void* d_out, int out_size, void* d_ws, size_t ws_size,
                              hipStream_t stream) {
  (void)in_sizes; (void)n_in; (void)out_size; (void)ws_size;
  const float* A_log = (const float*)d_in[2];
  const float* Ab_log = (const float*)d_in[3];

  float* ws = (float*)d_ws;
  float* xz = ws;                                      // BB*EE*LL (x-half reused as y_f)
  float* u_f = xz + (size_t)BB * EE * LL;              // BB*DN*LL
  float* u_r = u_f + (size_t)BB * DN * LL;             // BB*DN*LL
  float* dl_f = u_r + (size_t)BB * DN * LL;            // BB*DN*LL
  float* dl_r = dl_f + (size_t)BB * DN * LL;           // BB*DN*LL
  float* y_r = dl_r + (size_t)BB * DN * LL;            // BB*DN*LL
  float* Bt_f = y_r + (size_t)BB * DN * LL;            // BB*NS*LL
  float* Ct_f = Bt_f + (size_t)BB * NS * LL;
  float* Bt_r = Ct_f + (size_t)BB * NS * LL;
  float* Ct_r = Bt_r + (size_t)BB * NS * LL;
  float* hend = Ct_r + (size_t)BB * NS * LL;           // G*NC*NS
  float* h0 = hend + (size_t)2 * BB * DN * NC * NS;    // G*NC*NS
  float* sumdl = h0 + (size_t)2 * BB * DN * NC * NS;   // G*NC
  float* y_f = xz;                                     // alias: rows (b*EE+d)*LL

  const int G = 2 * BB * DN;

  for (int s = 0; s < 2; s++) {
    const int p = 4 + s * 14;
    const float* hin = (const float*)d_in[s];
    const float* in_w = (const float*)d_in[p + 0];
    const float* conv_w = (const float*)d_in[p + 1];
    const float* conv_b = (const float*)d_in[p + 2];
    const float* x_w = (const float*)d_in[p + 3];
    const float* dt_w = (const float*)d_in[p + 4];
    const float* dt_b = (const float*)d_in[p + 5];
    const float* Dp = (const float*)d_in[p + 6];
    const float* conv_w_b = (const float*)d_in[p + 7];
    const float* conv_b_b = (const float*)d_in[p + 8];
    const float* x_w_b = (const float*)d_in[p + 9];
    const float* dt_w_b = (const float*)d_in[p + 10];
    const float* dt_b_b = (const float*)d_in[p + 11];
    const float* Dp_b = (const float*)d_in[p + 12];
    const float* out_w = (const float*)d_in[p + 13];
    float* outp = (float*)d_out + (size_t)s * BB * LL * DM;

    hipLaunchKernelGGL(in_proj_kernel, dim3(LL / 128, EE / 128, BB), dim3(256), 0,
                       stream, hin, in_w, xz);
    hipLaunchKernelGGL(HIP_KERNEL_NAME(convproj_kernel<0>), dim3(LL / 32, BB),
                       dim3(256), 0, stream, xz, conv_w, conv_b, x_w, dt_w, dt_b,
                       u_f, dl_f, Bt_f, Ct_f);
    hipLaunchKernelGGL(HIP_KERNEL_NAME(convproj_kernel<1>), dim3(LL / 32, BB),
                       dim3(256), 0, stream, xz, conv_w_b, conv_b_b, x_w_b, dt_w_b,
                       dt_b_b, u_r, dl_r, Bt_r, Ct_r);
    hipLaunchKernelGGL(HIP_KERNEL_NAME(scan_phase_kernel<1>),
                       dim3((NC - 1) * G / 16), dim3(256), 0, stream, xz, u_f, u_r,
                       y_f, y_r, dl_f, dl_r, Bt_f, Ct_f, Bt_r, Ct_r, A_log, Ab_log,
                       Dp, Dp_b, hend, sumdl, h0);
    hipLaunchKernelGGL(scan_combine_kernel, dim3(G * NS / 256), dim3(256), 0, stream,
                       A_log, Ab_log, hend, sumdl, h0);
    hipLaunchKernelGGL(HIP_KERNEL_NAME(scan_phase_kernel<3>), dim3(NC * G / 16),
                       dim3(256), 0, stream, xz, u_f, u_r, y_f, y_r, dl_f, dl_r,
                       Bt_f, Ct_f, Bt_r, Ct_r, A_log, Ab_log, Dp, Dp_b, hend,
                       sumdl, h0);
    hipLaunchKernelGGL(out_proj_kernel, dim3(LL / 64, DM / 128, BB), dim3(256), 0,
                       stream, y_f, y_r, out_w, outp);
  }
}

// Round 5
// 979.260 us; speedup vs baseline: 2.6683x; 1.2512x over previous
//
#include <hip/hip_runtime.h>
#include <hip/hip_bf16.h>
#include <cstddef>

#define BB 4
#define LL 2048
#define DM 256
#define DN 512
#define EE 1024
#define NS 16
#define RK 16
#define NC2 64          // scan chunks
#define CL2 (LL / NC2)  // chunk length = 32

__device__ __forceinline__ float fsilu(float x) { return x / (1.0f + __expf(-x)); }
__device__ __forceinline__ float fsoftplus(float x) { return x > 20.0f ? x : log1pf(__expf(x)); }

// ---------------------------------------------------------------------------
// in_proj: xz[b][e][l] = sum_d in_w[e][d] * h[b][l][d]
// ---------------------------------------------------------------------------
__global__ __launch_bounds__(256) void in_proj_kernel(
    const float* __restrict__ h, const float* __restrict__ w, float* __restrict__ xz) {
  __shared__ float hs[128][33];   // [l][k]
  __shared__ float wsm[128][33];  // [e][k]
  const int b = blockIdx.z;
  const int e0 = blockIdx.y * 128;
  const int l0 = blockIdx.x * 128;
  const int tid = threadIdx.x;
  const int tx = tid & 15;  // l lane
  const int ty = tid >> 4;  // e group
  float acc[8][8] = {};     // [a(e)][c(l)]
  for (int dk = 0; dk < DM; dk += 32) {
#pragma unroll
    for (int it = 0; it < 16; it++) {
      int idx = it * 256 + tid;
      int i = idx >> 5;  // row (l or e)
      int j = idx & 31;  // k
      hs[i][j] = h[((size_t)b * LL + l0 + i) * DM + dk + j];
      wsm[i][j] = w[(size_t)(e0 + i) * DM + dk + j];
    }
    __syncthreads();
#pragma unroll
    for (int kk = 0; kk < 32; kk++) {
      float hv[8], wv[8];
#pragma unroll
      for (int c = 0; c < 8; c++) hv[c] = hs[tx + 16 * c][kk];
#pragma unroll
      for (int a = 0; a < 8; a++) wv[a] = wsm[ty * 8 + a][kk];
#pragma unroll
      for (int a = 0; a < 8; a++)
#pragma unroll
        for (int c = 0; c < 8; c++) acc[a][c] = fmaf(wv[a], hv[c], acc[a][c]);
    }
    __syncthreads();
  }
#pragma unroll
  for (int a = 0; a < 8; a++) {
#pragma unroll
    for (int c = 0; c < 8; c++)
      xz[((size_t)b * EE + e0 + ty * 8 + a) * LL + l0 + tx + 16 * c] = acc[a][c];
  }
}

// ---------------------------------------------------------------------------
// fused conv+silu -> u[b][l][d] (LDS transpose) -> x_dbl -> delta[b][l][d],
// B/C in [b][l][n]. xt padded to 33 for conflict-free transpose.
// ---------------------------------------------------------------------------
template <int REV>
__global__ __launch_bounds__(256) void convproj_kernel(
    const float* __restrict__ xz, const float* __restrict__ conv_w,
    const float* __restrict__ conv_b, const float* __restrict__ x_w,
    const float* __restrict__ dt_w, const float* __restrict__ dt_b,
    float* __restrict__ u_out, float* __restrict__ delta_out,
    float* __restrict__ Bc, float* __restrict__ Cc) {
  __shared__ float xt[DN][33];
  __shared__ float dtv[RK][32];
  const int b = blockIdx.y;
  const int l0 = blockIdx.x * 32;
  const int tid = threadIdx.x;
  const int lc = tid & 31;
  const int l = l0 + lc;

  // conv + silu -> LDS
#pragma unroll 4
  for (int i = 0; i < 64; i++) {
    int dd = i * 8 + (tid >> 5);
    const float* base = xz + ((size_t)b * EE + dd) * LL;
    float w0 = conv_w[dd * 4 + 0], w1 = conv_w[dd * 4 + 1];
    float w2 = conv_w[dd * 4 + 2], w3 = conv_w[dd * 4 + 3];
    float acc = conv_b[dd];
    if (REV) {
      acc = fmaf(w3, base[l], acc);
      if (l + 1 < LL) acc = fmaf(w2, base[l + 1], acc);
      if (l + 2 < LL) acc = fmaf(w1, base[l + 2], acc);
      if (l + 3 < LL) acc = fmaf(w0, base[l + 3], acc);
    } else {
      acc = fmaf(w3, base[l], acc);
      if (l - 1 >= 0) acc = fmaf(w2, base[l - 1], acc);
      if (l - 2 >= 0) acc = fmaf(w1, base[l - 2], acc);
      if (l - 3 >= 0) acc = fmaf(w0, base[l - 3], acc);
    }
    xt[dd][lc] = fsilu(acc);
  }
  __syncthreads();

  // transposed u store: [b][l][d], consecutive tid -> consecutive d
#pragma unroll 8
  for (int j = 0; j < 64; j++) {
    int idx = j * 256 + tid;
    int dd = idx & (DN - 1);
    int l2 = idx >> 9;
    u_out[((size_t)b * LL + l0 + l2) * DN + dd] = xt[dd][l2];
  }

  // x_dbl: 48 rows
  {
    const int rbase = tid >> 5;  // 0..7
    float accs[6] = {};
    for (int dd = 0; dd < DN; dd++) {
      float xval = xt[dd][lc];
#pragma unroll
      for (int i = 0; i < 6; i++)
        accs[i] = fmaf(x_w[(size_t)(rbase + i * 8) * DN + dd], xval, accs[i]);
    }
#pragma unroll
    for (int i = 0; i < 6; i++) {
      int r = rbase + i * 8;
      if (r < 16)
        dtv[r][lc] = accs[i];
      else if (r < 32)
        Bc[((size_t)b * LL + l) * NS + (r - 16)] = accs[i];
      else
        Cc[((size_t)b * LL + l) * NS + (r - 32)] = accs[i];
    }
  }
  __syncthreads();

  // delta = softplus(dt @ dt_w^T + dt_b) -> overwrite xt
  {
    float dtl[RK];
#pragma unroll
    for (int r = 0; r < RK; r++) dtl[r] = dtv[r][lc];
#pragma unroll 4
    for (int i = 0; i < 64; i++) {
      int dd = i * 8 + (tid >> 5);
      const float4* wrow = (const float4*)(dt_w + (size_t)dd * RK);
      float4 wq0 = wrow[0], wq1 = wrow[1], wq2 = wrow[2], wq3 = wrow[3];
      float acc = dt_b[dd];
      acc = fmaf(wq0.x, dtl[0], acc);  acc = fmaf(wq0.y, dtl[1], acc);
      acc = fmaf(wq0.z, dtl[2], acc);  acc = fmaf(wq0.w, dtl[3], acc);
      acc = fmaf(wq1.x, dtl[4], acc);  acc = fmaf(wq1.y, dtl[5], acc);
      acc = fmaf(wq1.z, dtl[6], acc);  acc = fmaf(wq1.w, dtl[7], acc);
      acc = fmaf(wq2.x, dtl[8], acc);  acc = fmaf(wq2.y, dtl[9], acc);
      acc = fmaf(wq2.z, dtl[10], acc); acc = fmaf(wq2.w, dtl[11], acc);
      acc = fmaf(wq3.x, dtl[12], acc); acc = fmaf(wq3.y, dtl[13], acc);
      acc = fmaf(wq3.z, dtl[14], acc); acc = fmaf(wq3.w, dtl[15], acc);
      xt[dd][lc] = fsoftplus(acc);
    }
  }
  __syncthreads();

  // transposed delta store
#pragma unroll 8
  for (int j = 0; j < 64; j++) {
    int idx = j * 256 + tid;
    int dd = idx & (DN - 1);
    int l2 = idx >> 9;
    delta_out[((size_t)b * LL + l0 + l2) * DN + dd] = xt[dd][l2];
  }
}

// ---------------------------------------------------------------------------
// Scan: lane = channel (d), all 16 states in registers. u/delta/y in [b][t][d]
// (coalesced), B/C in [b][t][n] (wave-uniform float4 broadcasts), z read
// strided from xz with on-the-fly silu. y written in-place over u.
// PHASE 1: store hend/sumdl. PHASE 3: start from h0 (in hend), write y.
// ---------------------------------------------------------------------------
#define HSTEP(n, Bcomp, Ccomp)                      \
  {                                                 \
    float e_ = __expf(dc * Av[n]);                  \
    h[n] = fmaf(e_, h[n], dlu * (Bcomp));           \
    if (PHASE == 3) acc = fmaf(h[n], (Ccomp), acc); \
  }

template <int PHASE>
__global__ __launch_bounds__(256) void scan_kernel(
    float* __restrict__ uy_f, float* __restrict__ uy_r,
    const float* __restrict__ dl_f, const float* __restrict__ dl_r,
    const float* __restrict__ xz, const float* __restrict__ B_f,
    const float* __restrict__ C_f, const float* __restrict__ B_r,
    const float* __restrict__ C_r, const float* __restrict__ A_log,
    const float* __restrict__ Ab_log, const float* __restrict__ D_f,
    const float* __restrict__ D_r, float* __restrict__ hend,
    float* __restrict__ sumdl) {
  const int G2 = 2 * BB * DN;                              // 4096
  const int ch = (blockIdx.x & 15) * 256 + threadIdx.x;    // channel
  const int chunk = blockIdx.x >> 4;                       // 0..NC2-1
  const bool rev = ch >= BB * DN;                          // uniform per block
  const int cid = rev ? ch - BB * DN : ch;
  const int b = cid >> 9;
  const int d = cid & (DN - 1);

  const float* Arow = (rev ? Ab_log : A_log) + d * NS;
  float Av[NS];
#pragma unroll
  for (int n = 0; n < NS; n++) Av[n] = -__expf(Arow[n]);
  const float Dd = (rev ? D_r : D_f)[d];

  float* uy = (rev ? uy_r : uy_f) + (size_t)b * LL * DN + d;
  const float* dlp = (rev ? dl_r : dl_f) + (size_t)b * LL * DN + d;
  const float* Bp = (rev ? B_r : B_f) + (size_t)b * LL * NS;
  const float* Cp = (rev ? C_r : C_f) + (size_t)b * LL * NS;
  const float* zp = xz + ((size_t)b * EE + DN + d) * LL;

  float h[NS];
  if (PHASE == 3) {
    const float* hp = hend + ((size_t)chunk * G2 + ch) * NS;
#pragma unroll
    for (int n = 0; n < NS; n++) h[n] = hp[n];
  } else {
#pragma unroll
    for (int n = 0; n < NS; n++) h[n] = 0.f;
  }

  const int tstep = rev ? -1 : 1;
  int t = rev ? (LL - 1 - CL2 * chunk) : (CL2 * chunk);
  float sdl = 0.f;
  float uc = uy[(size_t)t * DN];
  float dc = dlp[(size_t)t * DN];
  float zc = (PHASE == 3) ? zp[t] : 0.f;

  for (int s = 0; s < CL2; s++) {
    // 1-deep prefetch of the streaming loads (clamped; junk discarded at end)
    int tn = t + tstep;
    int tcl = tn < 0 ? 0 : (tn >= LL ? LL - 1 : tn);
    float un = uy[(size_t)tcl * DN];
    float dn_ = dlp[(size_t)tcl * DN];
    float zn = (PHASE == 3) ? zp[tcl] : 0.f;

    const float4* B4 = (const float4*)(Bp + (size_t)t * NS);
    float4 Bq0 = B4[0], Bq1 = B4[1], Bq2 = B4[2], Bq3 = B4[3];
    float4 Cq0 = {0, 0, 0, 0}, Cq1 = {0, 0, 0, 0}, Cq2 = {0, 0, 0, 0},
           Cq3 = {0, 0, 0, 0};
    if (PHASE == 3) {
      const float4* C4 = (const float4*)(Cp + (size_t)t * NS);
      Cq0 = C4[0]; Cq1 = C4[1]; Cq2 = C4[2]; Cq3 = C4[3];
    }
    const float dlu = dc * uc;
    float acc = 0.f;
    HSTEP(0, Bq0.x, Cq0.x)  HSTEP(1, Bq0.y, Cq0.y)
    HSTEP(2, Bq0.z, Cq0.z)  HSTEP(3, Bq0.w, Cq0.w)
    HSTEP(4, Bq1.x, Cq1.x)  HSTEP(5, Bq1.y, Cq1.y)
    HSTEP(6, Bq1.z, Cq1.z)  HSTEP(7, Bq1.w, Cq1.w)
    HSTEP(8, Bq2.x, Cq2.x)  HSTEP(9, Bq2.y, Cq2.y)
    HSTEP(10, Bq2.z, Cq2.z) HSTEP(11, Bq2.w, Cq2.w)
    HSTEP(12, Bq3.x, Cq3.x) HSTEP(13, Bq3.y, Cq3.y)
    HSTEP(14, Bq3.z, Cq3.z) HSTEP(15, Bq3.w, Cq3.w)
    if (PHASE == 1) sdl += dc;
    if (PHASE == 3) {
      float y = fmaf(uc, Dd, acc) * fsilu(zc);
      uy[(size_t)t * DN] = y;
    }
    t = tn; uc = un; dc = dn_; zc = zn;
  }
  if (PHASE == 1) {
    float* hp = hend + ((size_t)chunk * G2 + ch) * NS;
#pragma unroll
    for (int n = 0; n < NS; n++) hp[n] = h[n];
    sumdl[(size_t)chunk * G2 + ch] = sdl;
  }
}
#undef HSTEP

// Phase 2 (in-place): hend[c] <- h0[c] = H_{c-1}; H_c = exp(Av*sumdl[c])*H + hend[c]
__global__ __launch_bounds__(256) void scan_combine_kernel(
    const float* __restrict__ A_log, const float* __restrict__ Ab_log,
    float* __restrict__ hend, const float* __restrict__ sumdl) {
  const int G2 = 2 * BB * DN;
  const int gtid = blockIdx.x * 256 + threadIdx.x;
  const int ch = gtid >> 4;
  const int n = gtid & 15;
  const bool rev = ch >= BB * DN;
  const int d = ch & (DN - 1);
  const float Av = -__expf((rev ? Ab_log : A_log)[d * NS + n]);
  float H = 0.f;
  for (int c = 0; c < NC2; c++) {
    size_t idx = ((size_t)c * G2 + ch) * NS + n;
    float tmp = hend[idx];
    hend[idx] = H;
    if (c < NC2 - 1)
      H = fmaf(__expf(Av * sumdl[(size_t)c * G2 + ch]), H, tmp);
  }
}

// ---------------------------------------------------------------------------
// out_proj: out[b][l][m] = sum_d ow[m][d] * 0.5*(yf+yr)[b][l][d]
// y now [b][l][d]: the LDS tile load is directly coalesced over d (=k)
// ---------------------------------------------------------------------------
__global__ __launch_bounds__(256) void out_proj_kernel(
    const float* __restrict__ yf, const float* __restrict__ yr,
    const float* __restrict__ ow, float* __restrict__ outp) {
  __shared__ float ys[64][33];    // [l][k]
  __shared__ float wsm[128][33];  // [m][k]
  const int b = blockIdx.z;
  const int m0 = blockIdx.y * 128;
  const int l0 = blockIdx.x * 64;
  const int tid = threadIdx.x;
  const int tx = tid & 15;  // m lane
  const int ty = tid >> 4;  // l group
  float acc[8][4] = {};     // [cm][cl]
  for (int dk = 0; dk < DN; dk += 32) {
#pragma unroll
    for (int it = 0; it < 8; it++) {
      int idx = it * 256 + tid;
      int j = idx & 31;  // k (contiguous in y)
      int i = idx >> 5;  // l
      size_t yi = ((size_t)b * LL + l0 + i) * DN + dk + j;
      ys[i][j] = 0.5f * (yf[yi] + yr[yi]);
    }
#pragma unroll
    for (int it = 0; it < 16; it++) {
      int idx = it * 256 + tid;
      int j = idx & 31;  // k
      int i = idx >> 5;  // m
      wsm[i][j] = ow[(size_t)(m0 + i) * DN + dk + j];
    }
    __syncthreads();
#pragma unroll
    for (int kk = 0; kk < 32; kk++) {
      float wv[8], yv[4];
#pragma unroll
      for (int cm = 0; cm < 8; cm++) wv[cm] = wsm[tx + 16 * cm][kk];
#pragma unroll
      for (int cl = 0; cl < 4; cl++) yv[cl] = ys[ty * 4 + cl][kk];
#pragma unroll
      for (int cm = 0; cm < 8; cm++)
#pragma unroll
        for (int cl = 0; cl < 4; cl++) acc[cm][cl] = fmaf(wv[cm], yv[cl], acc[cm][cl]);
    }
    __syncthreads();
  }
#pragma unroll
  for (int cl = 0; cl < 4; cl++)
#pragma unroll
    for (int cm = 0; cm < 8; cm++)
      outp[((size_t)b * LL + l0 + ty * 4 + cl) * DM + m0 + tx + 16 * cm] = acc[cm][cl];
}

// ---------------------------------------------------------------------------
extern "C" void kernel_launch(void* const* d_in, const int* in_sizes, int n_in,
                              void* d_out, int out_size, void* d_ws, size_t ws_size,
                              hipStream_t stream) {
  (void)in_sizes; (void)n_in; (void)out_size; (void)ws_size;
  const float* A_log = (const float*)d_in[2];
  const float* Ab_log = (const float*)d_in[3];

  float* ws = (float*)d_ws;
  float* xz = ws;                                  // BB*EE*LL (z-half read by phase 3)
  float* u_f = xz + (size_t)BB * EE * LL;          // BB*LL*DN  (u -> y in place)
  float* u_r = u_f + (size_t)BB * LL * DN;         // BB*LL*DN
  float* dl_f = u_r + (size_t)BB * LL * DN;        // BB*LL*DN
  float* dl_r = dl_f + (size_t)BB * LL * DN;       // BB*LL*DN
  float* B_f = dl_r + (size_t)BB * LL * DN;        // BB*LL*NS
  float* C_f = B_f + (size_t)BB * LL * NS;
  float* B_r = C_f + (size_t)BB * LL * NS;
  float* C_r = B_r + (size_t)BB * LL * NS;
  float* hend = C_r + (size_t)BB * LL * NS;        // NC2*G2*NS (h0 in place)
  float* sumdl = hend + (size_t)NC2 * 2 * BB * DN * NS;  // NC2*G2

  for (int s = 0; s < 2; s++) {
    const int p = 4 + s * 14;
    const float* hin = (const float*)d_in[s];
    const float* in_w = (const float*)d_in[p + 0];
    const float* conv_w = (const float*)d_in[p + 1];
    const float* conv_b = (const float*)d_in[p + 2];
    const float* x_w = (const float*)d_in[p + 3];
    const float* dt_w = (const float*)d_in[p + 4];
    const float* dt_b = (const float*)d_in[p + 5];
    const float* Dp = (const float*)d_in[p + 6];
    const float* conv_w_b = (const float*)d_in[p + 7];
    const float* conv_b_b = (const float*)d_in[p + 8];
    const float* x_w_b = (const float*)d_in[p + 9];
    const float* dt_w_b = (const float*)d_in[p + 10];
    const float* dt_b_b = (const float*)d_in[p + 11];
    const float* Dp_b = (const float*)d_in[p + 12];
    const float* out_w = (const float*)d_in[p + 13];
    float* outp = (float*)d_out + (size_t)s * BB * LL * DM;

    hipLaunchKernelGGL(in_proj_kernel, dim3(LL / 128, EE / 128, BB), dim3(256), 0,
                       stream, hin, in_w, xz);
    hipLaunchKernelGGL(HIP_KERNEL_NAME(convproj_kernel<0>), dim3(LL / 32, BB),
                       dim3(256), 0, stream, xz, conv_w, conv_b, x_w, dt_w, dt_b,
                       u_f, dl_f, B_f, C_f);
    hipLaunchKernelGGL(HIP_KERNEL_NAME(convproj_kernel<1>), dim3(LL / 32, BB),
                       dim3(256), 0, stream, xz, conv_w_b, conv_b_b, x_w_b, dt_w_b,
                       dt_b_b, u_r, dl_r, B_r, C_r);
    hipLaunchKernelGGL(HIP_KERNEL_NAME(scan_kernel<1>), dim3(NC2 * 16), dim3(256), 0,
                       stream, u_f, u_r, dl_f, dl_r, xz, B_f, C_f, B_r, C_r, A_log,
                       Ab_log, Dp, Dp_b, hend, sumdl);
    hipLaunchKernelGGL(scan_combine_kernel, dim3(2 * BB * DN * NS / 256), dim3(256),
                       0, stream, A_log, Ab_log, hend, sumdl);
    hipLaunchKernelGGL(HIP_KERNEL_NAME(scan_kernel<3>), dim3(NC2 * 16), dim3(256), 0,
                       stream, u_f, u_r, dl_f, dl_r, xz, B_f, C_f, B_r, C_r, A_log,
                       Ab_log, Dp, Dp_b, hend, sumdl);
    hipLaunchKernelGGL(out_proj_kernel, dim3(LL / 64, DM / 128, BB), dim3(256), 0,
                       stream, u_f, u_r, out_w, outp);
  }
}

// Round 6
// 641.535 us; speedup vs baseline: 4.0730x; 1.5264x over previous
//
#include <hip/hip_runtime.h>
#include <hip/hip_bf16.h>
#include <cstddef>

#define BB 4
#define LL 2048
#define DM 256
#define DN 512
#define EE 1024
#define NS 16
#define RK 16
#define NC2 64          // scan chunks
#define CL2 (LL / NC2)  // chunk length = 32

__device__ __forceinline__ float fsilu(float x) { return x / (1.0f + __expf(-x)); }
__device__ __forceinline__ float fsoftplus(float x) { return x > 20.0f ? x : log1pf(__expf(x)); }

// ---------------------------------------------------------------------------
// in_proj. For e<DN (x-half): xz[b][e][l] row-major (conv reads rows).
// For e>=DN (z-half): z_t[b][l][e-DN] = silu(val)  (coalesced for the scan).
// z-blocks swap the microtile roles so the transposed store stays coalesced.
// ---------------------------------------------------------------------------
__global__ __launch_bounds__(256) void in_proj_kernel(
    const float* __restrict__ h, const float* __restrict__ w,
    float* __restrict__ xz, float* __restrict__ z_t) {
  __shared__ float hs[128][33];   // [l][k]
  __shared__ float wsm[128][33];  // [e][k]
  const int b = blockIdx.z;
  const int e0 = blockIdx.y * 128;
  const int l0 = blockIdx.x * 128;
  const int tid = threadIdx.x;
  const int tx = tid & 15;
  const int ty = tid >> 4;
  const bool zblk = (e0 >= DN);
  // lanebuf: rows indexed by lane (tx+16c); grpbuf: rows indexed by group (ty*8+a)
  float(*lanebuf)[33] = zblk ? wsm : hs;
  float(*grpbuf)[33] = zblk ? hs : wsm;
  float acc[8][8] = {};
  for (int dk = 0; dk < DM; dk += 32) {
#pragma unroll
    for (int it = 0; it < 16; it++) {
      int idx = it * 256 + tid;
      int i = idx >> 5;
      int j = idx & 31;
      hs[i][j] = h[((size_t)b * LL + l0 + i) * DM + dk + j];
      wsm[i][j] = w[(size_t)(e0 + i) * DM + dk + j];
    }
    __syncthreads();
#pragma unroll
    for (int kk = 0; kk < 32; kk++) {
      float bv[8], av[8];
#pragma unroll
      for (int c = 0; c < 8; c++) bv[c] = lanebuf[tx + 16 * c][kk];
#pragma unroll
      for (int a = 0; a < 8; a++) av[a] = grpbuf[ty * 8 + a][kk];
#pragma unroll
      for (int a = 0; a < 8; a++)
#pragma unroll
        for (int c = 0; c < 8; c++) acc[a][c] = fmaf(av[a], bv[c], acc[a][c]);
    }
    __syncthreads();
  }
  if (!zblk) {
#pragma unroll
    for (int a = 0; a < 8; a++)
#pragma unroll
      for (int c = 0; c < 8; c++)
        xz[((size_t)b * DN + e0 + ty * 8 + a) * LL + l0 + tx + 16 * c] = acc[a][c];
  } else {
#pragma unroll
    for (int a = 0; a < 8; a++)
#pragma unroll
      for (int c = 0; c < 8; c++)
        z_t[((size_t)b * LL + l0 + ty * 8 + a) * DN + (e0 - DN) + tx + 16 * c] =
            fsilu(acc[a][c]);
  }
}

// ---------------------------------------------------------------------------
// convproj (both branches, grid z = branch): d-chunked so everything reads
// from small LDS tiles. Per 64-d chunk: conv+silu -> xt_c; stage x_w chunk;
// u transposed store; accumulate x_dbl. Then dt->LDS, B/C->global, delta
// per chunk with staged dt_w. Outputs u/delta [b][l][d], B/C [b][l][n].
// ---------------------------------------------------------------------------
__global__ __launch_bounds__(256) void convproj_kernel(
    const float* __restrict__ xz,
    const float* __restrict__ cw_f, const float* __restrict__ cb_f,
    const float* __restrict__ xw_f, const float* __restrict__ dtw_f,
    const float* __restrict__ dtb_f,
    const float* __restrict__ cw_r, const float* __restrict__ cb_r,
    const float* __restrict__ xw_r, const float* __restrict__ dtw_r,
    const float* __restrict__ dtb_r,
    float* __restrict__ u_f, float* __restrict__ dl_f,
    float* __restrict__ B_f, float* __restrict__ C_f,
    float* __restrict__ u_r, float* __restrict__ dl_r,
    float* __restrict__ B_r, float* __restrict__ C_r) {
  __shared__ float xt_c[64][33];   // conv output / delta chunk
  __shared__ float xw_c[48][64];   // x_w k-chunk
  __shared__ float dtv[16][32];    // dt rows
  __shared__ float dtw_c[64][17];  // dt_w chunk
  __shared__ float dtb_s[DN];
  const int rev = blockIdx.z;
  const int b = blockIdx.y;
  const int l0 = blockIdx.x * 32;
  const int tid = threadIdx.x;
  const int lc = tid & 31;
  const int dg = tid >> 5;  // 0..7
  const int l = l0 + lc;

  const float* conv_w = rev ? cw_r : cw_f;
  const float* conv_b = rev ? cb_r : cb_f;
  const float* x_w = rev ? xw_r : xw_f;
  const float* dt_w = rev ? dtw_r : dtw_f;
  const float* dt_b = rev ? dtb_r : dtb_f;
  float* u_out = rev ? u_r : u_f;
  float* dl_out = rev ? dl_r : dl_f;
  float* B_out = rev ? B_r : B_f;
  float* C_out = rev ? C_r : C_f;

  dtb_s[tid] = dt_b[tid];
  dtb_s[tid + 256] = dt_b[tid + 256];

  float accs[6] = {};
  for (int dc = 0; dc < 8; dc++) {
    // conv + silu -> xt_c
#pragma unroll
    for (int i = 0; i < 8; i++) {
      int dd = dc * 64 + dg * 8 + i;
      const float* base = xz + ((size_t)b * DN + dd) * LL;
      float w0 = conv_w[dd * 4 + 0], w1 = conv_w[dd * 4 + 1];
      float w2 = conv_w[dd * 4 + 2], w3 = conv_w[dd * 4 + 3];
      float a0 = conv_b[dd];
      if (rev) {
        a0 = fmaf(w3, base[l], a0);
        if (l + 1 < LL) a0 = fmaf(w2, base[l + 1], a0);
        if (l + 2 < LL) a0 = fmaf(w1, base[l + 2], a0);
        if (l + 3 < LL) a0 = fmaf(w0, base[l + 3], a0);
      } else {
        a0 = fmaf(w3, base[l], a0);
        if (l - 1 >= 0) a0 = fmaf(w2, base[l - 1], a0);
        if (l - 2 >= 0) a0 = fmaf(w1, base[l - 2], a0);
        if (l - 3 >= 0) a0 = fmaf(w0, base[l - 3], a0);
      }
      xt_c[dg * 8 + i][lc] = fsilu(a0);
    }
    // stage x_w chunk [48][64] (coalesced rows)
#pragma unroll
    for (int j = 0; j < 12; j++) {
      int idx = j * 256 + tid;
      int r = idx >> 6;
      int k = idx & 63;
      xw_c[r][k] = x_w[(size_t)r * DN + dc * 64 + k];
    }
    __syncthreads();
    // u transposed store (coalesced 256B segments)
#pragma unroll
    for (int j = 0; j < 8; j++) {
      int idx = j * 256 + tid;
      int din = idx & 63;
      int l2 = idx >> 6;
      u_out[((size_t)b * LL + l0 + l2) * DN + dc * 64 + din] = xt_c[din][l2];
    }
    // x_dbl accumulate from LDS
#pragma unroll 4
    for (int kk = 0; kk < 64; kk++) {
      float xv = xt_c[kk][lc];
#pragma unroll
      for (int i = 0; i < 6; i++)
        accs[i] = fmaf(xw_c[dg + i * 8][kk], xv, accs[i]);
    }
    __syncthreads();
  }
  // dt -> LDS; B/C -> global
#pragma unroll
  for (int i = 0; i < 6; i++) {
    int r = dg + i * 8;
    if (r < 16)
      dtv[r][lc] = accs[i];
    else if (r < 32)
      B_out[((size_t)b * LL + l) * NS + (r - 16)] = accs[i];
    else
      C_out[((size_t)b * LL + l) * NS + (r - 32)] = accs[i];
  }
  __syncthreads();
  // delta per chunk
  for (int dc = 0; dc < 8; dc++) {
#pragma unroll
    for (int j = 0; j < 4; j++) {
      int idx = j * 256 + tid;
      int row = idx >> 4;
      int k = idx & 15;
      dtw_c[row][k] = dt_w[(size_t)(dc * 64 + row) * RK + k];
    }
    __syncthreads();
#pragma unroll
    for (int i = 0; i < 8; i++) {
      int dloc = dg * 8 + i;
      float a0 = dtb_s[dc * 64 + dloc];
#pragma unroll
      for (int k = 0; k < 16; k++) a0 = fmaf(dtw_c[dloc][k], dtv[k][lc], a0);
      xt_c[dloc][lc] = fsoftplus(a0);
    }
    __syncthreads();
#pragma unroll
    for (int j = 0; j < 8; j++) {
      int idx = j * 256 + tid;
      int din = idx & 63;
      int l2 = idx >> 6;
      dl_out[((size_t)b * LL + l0 + l2) * DN + dc * 64 + din] = xt_c[din][l2];
    }
  }
}

// ---------------------------------------------------------------------------
// Scan: lane = channel d, 16 states in registers. u/delta/z_t/y in [b][t][d]
// (all coalesced), B/C [b][t][n] wave-uniform float4. y in place over u.
// ---------------------------------------------------------------------------
#define HSTEP(n, Bcomp, Ccomp)                      \
  {                                                 \
    float e_ = __expf(dc * Av[n]);                  \
    h[n] = fmaf(e_, h[n], dlu * (Bcomp));           \
    if (PHASE == 3) acc = fmaf(h[n], (Ccomp), acc); \
  }

template <int PHASE>
__global__ __launch_bounds__(256) void scan_kernel(
    float* __restrict__ uy_f, float* __restrict__ uy_r,
    const float* __restrict__ dl_f, const float* __restrict__ dl_r,
    const float* __restrict__ z_t, const float* __restrict__ B_f,
    const float* __restrict__ C_f, const float* __restrict__ B_r,
    const float* __restrict__ C_r, const float* __restrict__ A_log,
    const float* __restrict__ Ab_log, const float* __restrict__ D_f,
    const float* __restrict__ D_r, float* __restrict__ hend,
    float* __restrict__ sumdl) {
  const int G2 = 2 * BB * DN;                            // 4096
  const int ch = (blockIdx.x & 15) * 256 + threadIdx.x;  // channel
  const int chunk = blockIdx.x >> 4;                     // 0..NC2-1
  const bool rev = ch >= BB * DN;                        // uniform per block
  const int cid = rev ? ch - BB * DN : ch;
  const int b = cid >> 9;
  const int d = cid & (DN - 1);

  const float* Arow = (rev ? Ab_log : A_log) + d * NS;
  float Av[NS];
#pragma unroll
  for (int n = 0; n < NS; n++) Av[n] = -__expf(Arow[n]);
  const float Dd = (rev ? D_r : D_f)[d];

  float* uy = (rev ? uy_r : uy_f) + (size_t)b * LL * DN + d;
  const float* dlp = (rev ? dl_r : dl_f) + (size_t)b * LL * DN + d;
  const float* Bp = (rev ? B_r : B_f) + (size_t)b * LL * NS;
  const float* Cp = (rev ? C_r : C_f) + (size_t)b * LL * NS;
  const float* zp = z_t + (size_t)b * LL * DN + d;

  float h[NS];
  if (PHASE == 3) {
    const float* hp = hend + ((size_t)chunk * G2 + ch) * NS;
#pragma unroll
    for (int n = 0; n < NS; n++) h[n] = hp[n];
  } else {
#pragma unroll
    for (int n = 0; n < NS; n++) h[n] = 0.f;
  }

  const int tstep = rev ? -1 : 1;
  int t = rev ? (LL - 1 - CL2 * chunk) : (CL2 * chunk);
  float sdl = 0.f;
  float uc = uy[(size_t)t * DN];
  float dc = dlp[(size_t)t * DN];
  float zc = (PHASE == 3) ? zp[(size_t)t * DN] : 0.f;

  for (int s = 0; s < CL2; s++) {
    int tn = t + tstep;
    int tcl = tn < 0 ? 0 : (tn >= LL ? LL - 1 : tn);
    float un = uy[(size_t)tcl * DN];
    float dn_ = dlp[(size_t)tcl * DN];
    float zn = (PHASE == 3) ? zp[(size_t)tcl * DN] : 0.f;

    const float4* B4 = (const float4*)(Bp + (size_t)t * NS);
    float4 Bq0 = B4[0], Bq1 = B4[1], Bq2 = B4[2], Bq3 = B4[3];
    float4 Cq0 = {0, 0, 0, 0}, Cq1 = {0, 0, 0, 0}, Cq2 = {0, 0, 0, 0},
           Cq3 = {0, 0, 0, 0};
    if (PHASE == 3) {
      const float4* C4 = (const float4*)(Cp + (size_t)t * NS);
      Cq0 = C4[0]; Cq1 = C4[1]; Cq2 = C4[2]; Cq3 = C4[3];
    }
    const float dlu = dc * uc;
    float acc = 0.f;
    HSTEP(0, Bq0.x, Cq0.x)  HSTEP(1, Bq0.y, Cq0.y)
    HSTEP(2, Bq0.z, Cq0.z)  HSTEP(3, Bq0.w, Cq0.w)
    HSTEP(4, Bq1.x, Cq1.x)  HSTEP(5, Bq1.y, Cq1.y)
    HSTEP(6, Bq1.z, Cq1.z)  HSTEP(7, Bq1.w, Cq1.w)
    HSTEP(8, Bq2.x, Cq2.x)  HSTEP(9, Bq2.y, Cq2.y)
    HSTEP(10, Bq2.z, Cq2.z) HSTEP(11, Bq2.w, Cq2.w)
    HSTEP(12, Bq3.x, Cq3.x) HSTEP(13, Bq3.y, Cq3.y)
    HSTEP(14, Bq3.z, Cq3.z) HSTEP(15, Bq3.w, Cq3.w)
    if (PHASE == 1) sdl += dc;
    if (PHASE == 3) {
      float y = fmaf(uc, Dd, acc) * zc;
      uy[(size_t)t * DN] = y;
    }
    t = tn; uc = un; dc = dn_; zc = zn;
  }
  if (PHASE == 1) {
    float* hp = hend + ((size_t)chunk * G2 + ch) * NS;
#pragma unroll
    for (int n = 0; n < NS; n++) hp[n] = h[n];
    sumdl[(size_t)chunk * G2 + ch] = sdl;
  }
}
#undef HSTEP

// Phase 2 (in-place): hend[c] <- h0[c] = H_{c-1}; H_c = exp(Av*sumdl[c])*H + hend[c]
__global__ __launch_bounds__(256) void scan_combine_kernel(
    const float* __restrict__ A_log, const float* __restrict__ Ab_log,
    float* __restrict__ hend, const float* __restrict__ sumdl) {
  const int G2 = 2 * BB * DN;
  const int gtid = blockIdx.x * 256 + threadIdx.x;
  const int ch = gtid >> 4;
  const int n = gtid & 15;
  const bool rev = ch >= BB * DN;
  const int d = ch & (DN - 1);
  const float Av = -__expf((rev ? Ab_log : A_log)[d * NS + n]);
  float H = 0.f;
  for (int c = 0; c < NC2; c++) {
    size_t idx = ((size_t)c * G2 + ch) * NS + n;
    float tmp = hend[idx];
    hend[idx] = H;
    if (c < NC2 - 1)
      H = fmaf(__expf(Av * sumdl[(size_t)c * G2 + ch]), H, tmp);
  }
}

// ---------------------------------------------------------------------------
// out_proj: out[b][l][m] = sum_d ow[m][d] * 0.5*(yf+yr)[b][l][d]
// ---------------------------------------------------------------------------
__global__ __launch_bounds__(256) void out_proj_kernel(
    const float* __restrict__ yf, const float* __restrict__ yr,
    const float* __restrict__ ow, float* __restrict__ outp) {
  __shared__ float ys[64][33];    // [l][k]
  __shared__ float wsm[128][33];  // [m][k]
  const int b = blockIdx.z;
  const int m0 = blockIdx.y * 128;
  const int l0 = blockIdx.x * 64;
  const int tid = threadIdx.x;
  const int tx = tid & 15;  // m lane
  const int ty = tid >> 4;  // l group
  float acc[8][4] = {};     // [cm][cl]
  for (int dk = 0; dk < DN; dk += 32) {
#pragma unroll
    for (int it = 0; it < 8; it++) {
      int idx = it * 256 + tid;
      int j = idx & 31;  // k (contiguous in y)
      int i = idx >> 5;  // l
      size_t yi = ((size_t)b * LL + l0 + i) * DN + dk + j;
      ys[i][j] = 0.5f * (yf[yi] + yr[yi]);
    }
#pragma unroll
    for (int it = 0; it < 16; it++) {
      int idx = it * 256 + tid;
      int j = idx & 31;  // k
      int i = idx >> 5;  // m
      wsm[i][j] = ow[(size_t)(m0 + i) * DN + dk + j];
    }
    __syncthreads();
#pragma unroll
    for (int kk = 0; kk < 32; kk++) {
      float wv[8], yv[4];
#pragma unroll
      for (int cm = 0; cm < 8; cm++) wv[cm] = wsm[tx + 16 * cm][kk];
#pragma unroll
      for (int cl = 0; cl < 4; cl++) yv[cl] = ys[ty * 4 + cl][kk];
#pragma unroll
      for (int cm = 0; cm < 8; cm++)
#pragma unroll
        for (int cl = 0; cl < 4; cl++) acc[cm][cl] = fmaf(wv[cm], yv[cl], acc[cm][cl]);
    }
    __syncthreads();
  }
#pragma unroll
  for (int cl = 0; cl < 4; cl++)
#pragma unroll
    for (int cm = 0; cm < 8; cm++)
      outp[((size_t)b * LL + l0 + ty * 4 + cl) * DM + m0 + tx + 16 * cm] = acc[cm][cl];
}

// ---------------------------------------------------------------------------
extern "C" void kernel_launch(void* const* d_in, const int* in_sizes, int n_in,
                              void* d_out, int out_size, void* d_ws, size_t ws_size,
                              hipStream_t stream) {
  (void)in_sizes; (void)n_in; (void)out_size; (void)ws_size;
  const float* A_log = (const float*)d_in[2];
  const float* Ab_log = (const float*)d_in[3];

  float* ws = (float*)d_ws;
  float* xz = ws;                              // BB*DN*LL  (x rows only)
  float* z_t = xz + (size_t)BB * DN * LL;      // BB*LL*DN  silu(z) transposed
  float* u_f = z_t + (size_t)BB * LL * DN;     // BB*LL*DN  (u -> y in place)
  float* u_r = u_f + (size_t)BB * LL * DN;
  float* dl_f = u_r + (size_t)BB * LL * DN;
  float* dl_r = dl_f + (size_t)BB * LL * DN;
  float* B_f = dl_r + (size_t)BB * LL * DN;    // BB*LL*NS
  float* C_f = B_f + (size_t)BB * LL * NS;
  float* B_r = C_f + (size_t)BB * LL * NS;
  float* C_r = B_r + (size_t)BB * LL * NS;
  float* hend = C_r + (size_t)BB * LL * NS;    // NC2*G2*NS
  float* sumdl = hend + (size_t)NC2 * 2 * BB * DN * NS;  // NC2*G2

  for (int s = 0; s < 2; s++) {
    const int p = 4 + s * 14;
    const float* hin = (const float*)d_in[s];
    const float* in_w = (const float*)d_in[p + 0];
    const float* conv_w = (const float*)d_in[p + 1];
    const float* conv_b = (const float*)d_in[p + 2];
    const float* x_w = (const float*)d_in[p + 3];
    const float* dt_w = (const float*)d_in[p + 4];
    const float* dt_b = (const float*)d_in[p + 5];
    const float* Dp = (const float*)d_in[p + 6];
    const float* conv_w_b = (const float*)d_in[p + 7];
    const float* conv_b_b = (const float*)d_in[p + 8];
    const float* x_w_b = (const float*)d_in[p + 9];
    const float* dt_w_b = (const float*)d_in[p + 10];
    const float* dt_b_b = (const float*)d_in[p + 11];
    const float* Dp_b = (const float*)d_in[p + 12];
    const float* out_w = (const float*)d_in[p + 13];
    float* outp = (float*)d_out + (size_t)s * BB * LL * DM;

    hipLaunchKernelGGL(in_proj_kernel, dim3(LL / 128, EE / 128, BB), dim3(256), 0,
                       stream, hin, in_w, xz, z_t);
    hipLaunchKernelGGL(convproj_kernel, dim3(LL / 32, BB, 2), dim3(256), 0, stream,
                       xz, conv_w, conv_b, x_w, dt_w, dt_b, conv_w_b, conv_b_b,
                       x_w_b, dt_w_b, dt_b_b, u_f, dl_f, B_f, C_f, u_r, dl_r, B_r,
                       C_r);
    hipLaunchKernelGGL(HIP_KERNEL_NAME(scan_kernel<1>), dim3(NC2 * 16), dim3(256), 0,
                       stream, u_f, u_r, dl_f, dl_r, z_t, B_f, C_f, B_r, C_r, A_log,
                       Ab_log, Dp, Dp_b, hend, sumdl);
    hipLaunchKernelGGL(scan_combine_kernel, dim3(2 * BB * DN * NS / 256), dim3(256),
                       0, stream, A_log, Ab_log, hend, sumdl);
    hipLaunchKernelGGL(HIP_KERNEL_NAME(scan_kernel<3>), dim3(NC2 * 16), dim3(256), 0,
                       stream, u_f, u_r, dl_f, dl_r, z_t, B_f, C_f, B_r, C_r, A_log,
                       Ab_log, Dp, Dp_b, hend, sumdl);
    hipLaunchKernelGGL(out_proj_kernel, dim3(LL / 64, DM / 128, BB), dim3(256), 0,
                       stream, u_f, u_r, out_w, outp);
  }
}

// Round 7
// 427.550 us; speedup vs baseline: 6.1115x; 1.5005x over previous
//
#include <hip/hip_runtime.h>
#include <hip/hip_bf16.h>
#include <cstddef>

#define BB 4
#define LL 2048
#define DM 256
#define DN 512
#define EE 1024
#define NS 16
#define RK 16
#define NC2 64          // scan chunks
#define CL2 (LL / NC2)  // chunk length = 32

typedef __attribute__((ext_vector_type(8))) short bf16x8;
typedef __attribute__((ext_vector_type(8))) unsigned short ushort8;
typedef __attribute__((ext_vector_type(4))) float f32x4;

__device__ __forceinline__ float fsilu(float x) { return x / (1.0f + __expf(-x)); }
__device__ __forceinline__ float fsoftplus(float x) { return x > 20.0f ? x : log1pf(__expf(x)); }
__device__ __forceinline__ unsigned short f2bf(float x) {  // RNE float->bf16
  union { float f; unsigned int u; } v; v.f = x;
  unsigned int r = v.u + 0x7fffu + ((v.u >> 16) & 1u);
  return (unsigned short)(r >> 16);
}

// ---------------------------------------------------------------------------
// in_proj via bf16 MFMA. Block: 128e x 128l, 4 waves (2x2), wave 64x64 =
// 4x4 MFMA 16x16x32. x-blocks (e<DN): C[e][l] -> xz[b][e][l].
// z-blocks: swap A/B so C[l][d] -> z_t[b][l][d] = silu (coalesced).
// ---------------------------------------------------------------------------
__global__ __launch_bounds__(256) void in_proj_mfma(
    const float* __restrict__ h, const float* __restrict__ w,
    float* __restrict__ xz, float* __restrict__ z_t) {
  __shared__ unsigned short ht[128][40];  // [l][k] bf16, 80B row (16B aligned)
  __shared__ unsigned short wt[128][40];  // [e][k]
  const int b = blockIdx.z;
  const int e0 = blockIdx.y * 128;
  const int l0 = blockIdx.x * 128;
  const int tid = threadIdx.x;
  const int lane = tid & 63;
  const int wid = tid >> 6;
  const int wm = wid >> 1, wn = wid & 1;
  const bool zblk = (e0 >= DN);
  const int krow = (lane >> 4) * 8;
  const int rlo = lane & 15;

  f32x4 acc[4][4];
#pragma unroll
  for (int i = 0; i < 4; i++)
#pragma unroll
    for (int j = 0; j < 4; j++) acc[i][j] = (f32x4){0.f, 0.f, 0.f, 0.f};

  for (int dk = 0; dk < DM; dk += 32) {
#pragma unroll
    for (int it = 0; it < 2; it++) {
      int idx = it * 256 + tid;
      int row = idx >> 2;
      int seg = (idx & 3) * 8;
      const float* hp = h + ((size_t)b * LL + l0 + row) * DM + dk + seg;
      float4 ha = *(const float4*)hp, hb = *(const float4*)(hp + 4);
      ushort8 hv;
      hv[0] = f2bf(ha.x); hv[1] = f2bf(ha.y); hv[2] = f2bf(ha.z); hv[3] = f2bf(ha.w);
      hv[4] = f2bf(hb.x); hv[5] = f2bf(hb.y); hv[6] = f2bf(hb.z); hv[7] = f2bf(hb.w);
      *(ushort8*)&ht[row][seg] = hv;
      const float* wp = w + (size_t)(e0 + row) * DM + dk + seg;
      float4 wa = *(const float4*)wp, wb = *(const float4*)(wp + 4);
      ushort8 wv;
      wv[0] = f2bf(wa.x); wv[1] = f2bf(wa.y); wv[2] = f2bf(wa.z); wv[3] = f2bf(wa.w);
      wv[4] = f2bf(wb.x); wv[5] = f2bf(wb.y); wv[6] = f2bf(wb.z); wv[7] = f2bf(wb.w);
      *(ushort8*)&wt[row][seg] = wv;
    }
    __syncthreads();
    unsigned short (*Ab)[40] = zblk ? ht : wt;
    unsigned short (*Bb)[40] = zblk ? wt : ht;
    bf16x8 af[4], bfr[4];
#pragma unroll
    for (int mt = 0; mt < 4; mt++)
      af[mt] = *(bf16x8*)&Ab[wm * 64 + mt * 16 + rlo][krow];
#pragma unroll
    for (int nt = 0; nt < 4; nt++)
      bfr[nt] = *(bf16x8*)&Bb[wn * 64 + nt * 16 + rlo][krow];
#pragma unroll
    for (int mt = 0; mt < 4; mt++)
#pragma unroll
      for (int nt = 0; nt < 4; nt++)
        acc[mt][nt] = __builtin_amdgcn_mfma_f32_16x16x32_bf16(
            af[mt], bfr[nt], acc[mt][nt], 0, 0, 0);
    __syncthreads();
  }
  if (!zblk) {
#pragma unroll
    for (int mt = 0; mt < 4; mt++)
#pragma unroll
      for (int nt = 0; nt < 4; nt++)
#pragma unroll
        for (int r = 0; r < 4; r++) {
          int e = e0 + wm * 64 + mt * 16 + (lane >> 4) * 4 + r;
          int l = l0 + wn * 64 + nt * 16 + rlo;
          xz[((size_t)b * DN + e) * LL + l] = acc[mt][nt][r];
        }
  } else {
#pragma unroll
    for (int mt = 0; mt < 4; mt++)
#pragma unroll
      for (int nt = 0; nt < 4; nt++)
#pragma unroll
        for (int r = 0; r < 4; r++) {
          int l = l0 + wm * 64 + mt * 16 + (lane >> 4) * 4 + r;
          int d = (e0 - DN) + wn * 64 + nt * 16 + rlo;
          z_t[((size_t)b * LL + l) * DN + d] = fsilu(acc[mt][nt][r]);
        }
  }
}

// ---------------------------------------------------------------------------
// convproj: l-tile 16 (1024 blocks = 4/CU). lc = tid&15 (l), dg = tid>>4.
// Row mapping r = dg / dg+16 / dg+32 -> dt / B / C exactly.
// ---------------------------------------------------------------------------
__global__ __launch_bounds__(256) void convproj_kernel(
    const float* __restrict__ xz,
    const float* __restrict__ cw_f, const float* __restrict__ cb_f,
    const float* __restrict__ xw_f, const float* __restrict__ dtw_f,
    const float* __restrict__ dtb_f,
    const float* __restrict__ cw_r, const float* __restrict__ cb_r,
    const float* __restrict__ xw_r, const float* __restrict__ dtw_r,
    const float* __restrict__ dtb_r,
    float* __restrict__ u_f, float* __restrict__ dl_f,
    float* __restrict__ B_f, float* __restrict__ C_f,
    float* __restrict__ u_r, float* __restrict__ dl_r,
    float* __restrict__ B_r, float* __restrict__ C_r) {
  __shared__ float xt_c[64][17];   // conv output / delta chunk
  __shared__ float xw_c[48][65];   // x_w k-chunk (pad 65: no bank aliasing)
  __shared__ float dtv[16][17];    // dt rows
  __shared__ float dtw_c[64][17];  // dt_w chunk
  __shared__ float dtb_s[DN];
  const int rev = blockIdx.z;
  const int b = blockIdx.y;
  const int l0 = blockIdx.x * 16;
  const int tid = threadIdx.x;
  const int lc = tid & 15;
  const int dg = tid >> 4;  // 0..15
  const int l = l0 + lc;

  const float* conv_w = rev ? cw_r : cw_f;
  const float* conv_b = rev ? cb_r : cb_f;
  const float* x_w = rev ? xw_r : xw_f;
  const float* dt_w = rev ? dtw_r : dtw_f;
  const float* dt_b = rev ? dtb_r : dtb_f;
  float* u_out = rev ? u_r : u_f;
  float* dl_out = rev ? dl_r : dl_f;
  float* B_out = rev ? B_r : B_f;
  float* C_out = rev ? C_r : C_f;

  dtb_s[tid] = dt_b[tid];
  dtb_s[tid + 256] = dt_b[tid + 256];

  float acc_dt = 0.f, acc_B = 0.f, acc_C = 0.f;
  for (int dc = 0; dc < 8; dc++) {
    // conv + silu -> xt_c (4 d-rows per thread)
#pragma unroll
    for (int i = 0; i < 4; i++) {
      int dd = dc * 64 + dg * 4 + i;
      const float* base = xz + ((size_t)b * DN + dd) * LL;
      float w0 = conv_w[dd * 4 + 0], w1 = conv_w[dd * 4 + 1];
      float w2 = conv_w[dd * 4 + 2], w3 = conv_w[dd * 4 + 3];
      float a0 = conv_b[dd];
      if (rev) {
        a0 = fmaf(w3, base[l], a0);
        if (l + 1 < LL) a0 = fmaf(w2, base[l + 1], a0);
        if (l + 2 < LL) a0 = fmaf(w1, base[l + 2], a0);
        if (l + 3 < LL) a0 = fmaf(w0, base[l + 3], a0);
      } else {
        a0 = fmaf(w3, base[l], a0);
        if (l - 1 >= 0) a0 = fmaf(w2, base[l - 1], a0);
        if (l - 2 >= 0) a0 = fmaf(w1, base[l - 2], a0);
        if (l - 3 >= 0) a0 = fmaf(w0, base[l - 3], a0);
      }
      xt_c[dg * 4 + i][lc] = fsilu(a0);
    }
    // stage x_w chunk [48][64]
#pragma unroll
    for (int j = 0; j < 12; j++) {
      int idx = j * 256 + tid;
      int r = idx >> 6;
      int k = idx & 63;
      xw_c[r][k] = x_w[(size_t)r * DN + dc * 64 + k];
    }
    __syncthreads();
    // u transposed store (coalesced 256B segments)
#pragma unroll
    for (int j = 0; j < 4; j++) {
      int idx = j * 256 + tid;
      int din = idx & 63;
      int l2 = idx >> 6;
      u_out[((size_t)b * LL + l0 + l2) * DN + dc * 64 + din] = xt_c[din][l2];
    }
    // x_dbl accumulate from LDS
#pragma unroll 4
    for (int kk = 0; kk < 64; kk++) {
      float xv = xt_c[kk][lc];
      acc_dt = fmaf(xw_c[dg][kk], xv, acc_dt);
      acc_B = fmaf(xw_c[dg + 16][kk], xv, acc_B);
      acc_C = fmaf(xw_c[dg + 32][kk], xv, acc_C);
    }
    __syncthreads();
  }
  dtv[dg][lc] = acc_dt;
  B_out[((size_t)b * LL + l) * NS + dg] = acc_B;
  C_out[((size_t)b * LL + l) * NS + dg] = acc_C;
  __syncthreads();
  // delta per chunk
  for (int dc = 0; dc < 8; dc++) {
#pragma unroll
    for (int j = 0; j < 4; j++) {
      int idx = j * 256 + tid;
      int row = idx >> 4;
      int k = idx & 15;
      dtw_c[row][k] = dt_w[(size_t)(dc * 64 + row) * RK + k];
    }
    __syncthreads();
#pragma unroll
    for (int i = 0; i < 4; i++) {
      int dloc = dg * 4 + i;
      float a0 = dtb_s[dc * 64 + dloc];
#pragma unroll
      for (int k = 0; k < 16; k++) a0 = fmaf(dtw_c[dloc][k], dtv[k][lc], a0);
      xt_c[dloc][lc] = fsoftplus(a0);
    }
    __syncthreads();
#pragma unroll
    for (int j = 0; j < 4; j++) {
      int idx = j * 256 + tid;
      int din = idx & 63;
      int l2 = idx >> 6;
      dl_out[((size_t)b * LL + l0 + l2) * DN + dc * 64 + din] = xt_c[din][l2];
    }
  }
}

// ---------------------------------------------------------------------------
// Scan: lane = channel d, 16 states in registers. u/delta/z_t/y in [b][t][d]
// (all coalesced), B/C [b][t][n] wave-uniform float4. y in place over u.
// ---------------------------------------------------------------------------
#define HSTEP(n, Bcomp, Ccomp)                      \
  {                                                 \
    float e_ = __expf(dc * Av[n]);                  \
    h[n] = fmaf(e_, h[n], dlu * (Bcomp));           \
    if (PHASE == 3) acc = fmaf(h[n], (Ccomp), acc); \
  }

template <int PHASE>
__global__ __launch_bounds__(256) void scan_kernel(
    float* __restrict__ uy_f, float* __restrict__ uy_r,
    const float* __restrict__ dl_f, const float* __restrict__ dl_r,
    const float* __restrict__ z_t, const float* __restrict__ B_f,
    const float* __restrict__ C_f, const float* __restrict__ B_r,
    const float* __restrict__ C_r, const float* __restrict__ A_log,
    const float* __restrict__ Ab_log, const float* __restrict__ D_f,
    const float* __restrict__ D_r, float* __restrict__ hend,
    float* __restrict__ sumdl) {
  const int G2 = 2 * BB * DN;                            // 4096
  const int ch = (blockIdx.x & 15) * 256 + threadIdx.x;  // channel
  const int chunk = blockIdx.x >> 4;                     // 0..NC2-1
  const bool rev = ch >= BB * DN;                        // uniform per block
  const int cid = rev ? ch - BB * DN : ch;
  const int b = cid >> 9;
  const int d = cid & (DN - 1);

  const float* Arow = (rev ? Ab_log : A_log) + d * NS;
  float Av[NS];
#pragma unroll
  for (int n = 0; n < NS; n++) Av[n] = -__expf(Arow[n]);
  const float Dd = (rev ? D_r : D_f)[d];

  float* uy = (rev ? uy_r : uy_f) + (size_t)b * LL * DN + d;
  const float* dlp = (rev ? dl_r : dl_f) + (size_t)b * LL * DN + d;
  const float* Bp = (rev ? B_r : B_f) + (size_t)b * LL * NS;
  const float* Cp = (rev ? C_r : C_f) + (size_t)b * LL * NS;
  const float* zp = z_t + (size_t)b * LL * DN + d;

  float h[NS];
  if (PHASE == 3) {
    const float* hp = hend + ((size_t)chunk * G2 + ch) * NS;
#pragma unroll
    for (int n = 0; n < NS; n++) h[n] = hp[n];
  } else {
#pragma unroll
    for (int n = 0; n < NS; n++) h[n] = 0.f;
  }

  const int tstep = rev ? -1 : 1;
  int t = rev ? (LL - 1 - CL2 * chunk) : (CL2 * chunk);
  float sdl = 0.f;
  float uc = uy[(size_t)t * DN];
  float dc = dlp[(size_t)t * DN];
  float zc = (PHASE == 3) ? zp[(size_t)t * DN] : 0.f;

  for (int s = 0; s < CL2; s++) {
    int tn = t + tstep;
    int tcl = tn < 0 ? 0 : (tn >= LL ? LL - 1 : tn);
    float un = uy[(size_t)tcl * DN];
    float dn_ = dlp[(size_t)tcl * DN];
    float zn = (PHASE == 3) ? zp[(size_t)tcl * DN] : 0.f;

    const float4* B4 = (const float4*)(Bp + (size_t)t * NS);
    float4 Bq0 = B4[0], Bq1 = B4[1], Bq2 = B4[2], Bq3 = B4[3];
    float4 Cq0 = {0, 0, 0, 0}, Cq1 = {0, 0, 0, 0}, Cq2 = {0, 0, 0, 0},
           Cq3 = {0, 0, 0, 0};
    if (PHASE == 3) {
      const float4* C4 = (const float4*)(Cp + (size_t)t * NS);
      Cq0 = C4[0]; Cq1 = C4[1]; Cq2 = C4[2]; Cq3 = C4[3];
    }
    const float dlu = dc * uc;
    float acc = 0.f;
    HSTEP(0, Bq0.x, Cq0.x)  HSTEP(1, Bq0.y, Cq0.y)
    HSTEP(2, Bq0.z, Cq0.z)  HSTEP(3, Bq0.w, Cq0.w)
    HSTEP(4, Bq1.x, Cq1.x)  HSTEP(5, Bq1.y, Cq1.y)
    HSTEP(6, Bq1.z, Cq1.z)  HSTEP(7, Bq1.w, Cq1.w)
    HSTEP(8, Bq2.x, Cq2.x)  HSTEP(9, Bq2.y, Cq2.y)
    HSTEP(10, Bq2.z, Cq2.z) HSTEP(11, Bq2.w, Cq2.w)
    HSTEP(12, Bq3.x, Cq3.x) HSTEP(13, Bq3.y, Cq3.y)
    HSTEP(14, Bq3.z, Cq3.z) HSTEP(15, Bq3.w, Cq3.w)
    if (PHASE == 1) sdl += dc;
    if (PHASE == 3) {
      float y = fmaf(uc, Dd, acc) * zc;
      uy[(size_t)t * DN] = y;
    }
    t = tn; uc = un; dc = dn_; zc = zn;
  }
  if (PHASE == 1) {
    float* hp = hend + ((size_t)chunk * G2 + ch) * NS;
#pragma unroll
    for (int n = 0; n < NS; n++) hp[n] = h[n];
    sumdl[(size_t)chunk * G2 + ch] = sdl;
  }
}
#undef HSTEP

// Phase 2 (in-place): hend[c] <- h0[c] = H_{c-1}; H_c = exp(Av*sumdl[c])*H + hend[c]
__global__ __launch_bounds__(256) void scan_combine_kernel(
    const float* __restrict__ A_log, const float* __restrict__ Ab_log,
    float* __restrict__ hend, const float* __restrict__ sumdl) {
  const int G2 = 2 * BB * DN;
  const int gtid = blockIdx.x * 256 + threadIdx.x;
  const int ch = gtid >> 4;
  const int n = gtid & 15;
  const bool rev = ch >= BB * DN;
  const int d = ch & (DN - 1);
  const float Av = -__expf((rev ? Ab_log : A_log)[d * NS + n]);
  float H = 0.f;
  for (int c = 0; c < NC2; c++) {
    size_t idx = ((size_t)c * G2 + ch) * NS + n;
    float tmp = hend[idx];
    hend[idx] = H;
    if (c < NC2 - 1)
      H = fmaf(__expf(Av * sumdl[(size_t)c * G2 + ch]), H, tmp);
  }
}

// ---------------------------------------------------------------------------
// out_proj via bf16 MFMA: C[l][m] = sum_d 0.5*(yf+yr)[b][l][d] * ow[m][d].
// Block 64l x 64m, 4 waves (2x2), wave 32x32 = 2x2 MFMA tiles, K=512.
// ---------------------------------------------------------------------------
__global__ __launch_bounds__(256) void out_proj_mfma(
    const float* __restrict__ yf, const float* __restrict__ yr,
    const float* __restrict__ ow, float* __restrict__ outp) {
  __shared__ unsigned short yt[64][40];
  __shared__ unsigned short wo[64][40];
  const int b = blockIdx.z;
  const int m0 = blockIdx.y * 64;
  const int l0 = blockIdx.x * 64;
  const int tid = threadIdx.x;
  const int lane = tid & 63;
  const int wid = tid >> 6;
  const int wm = wid >> 1, wn = wid & 1;
  const int krow = (lane >> 4) * 8;
  const int rlo = lane & 15;

  f32x4 acc[2][2];
#pragma unroll
  for (int i = 0; i < 2; i++)
#pragma unroll
    for (int j = 0; j < 2; j++) acc[i][j] = (f32x4){0.f, 0.f, 0.f, 0.f};

  for (int dk = 0; dk < DN; dk += 32) {
    {
      int row = tid >> 2;
      int seg = (tid & 3) * 8;
      const float* ya = yf + ((size_t)b * LL + l0 + row) * DN + dk + seg;
      const float* yb = yr + ((size_t)b * LL + l0 + row) * DN + dk + seg;
      float4 a0 = *(const float4*)ya, a1 = *(const float4*)(ya + 4);
      float4 b0 = *(const float4*)yb, b1 = *(const float4*)(yb + 4);
      ushort8 yv;
      yv[0] = f2bf(0.5f * (a0.x + b0.x)); yv[1] = f2bf(0.5f * (a0.y + b0.y));
      yv[2] = f2bf(0.5f * (a0.z + b0.z)); yv[3] = f2bf(0.5f * (a0.w + b0.w));
      yv[4] = f2bf(0.5f * (a1.x + b1.x)); yv[5] = f2bf(0.5f * (a1.y + b1.y));
      yv[6] = f2bf(0.5f * (a1.z + b1.z)); yv[7] = f2bf(0.5f * (a1.w + b1.w));
      *(ushort8*)&yt[row][seg] = yv;
      const float* wp = ow + (size_t)(m0 + row) * DN + dk + seg;
      float4 w0 = *(const float4*)wp, w1 = *(const float4*)(wp + 4);
      ushort8 wv;
      wv[0] = f2bf(w0.x); wv[1] = f2bf(w0.y); wv[2] = f2bf(w0.z); wv[3] = f2bf(w0.w);
      wv[4] = f2bf(w1.x); wv[5] = f2bf(w1.y); wv[6] = f2bf(w1.z); wv[7] = f2bf(w1.w);
      *(ushort8*)&wo[row][seg] = wv;
    }
    __syncthreads();
    bf16x8 a0 = *(bf16x8*)&yt[wm * 32 + rlo][krow];
    bf16x8 a1 = *(bf16x8*)&yt[wm * 32 + 16 + rlo][krow];
    bf16x8 b0 = *(bf16x8*)&wo[wn * 32 + rlo][krow];
    bf16x8 b1 = *(bf16x8*)&wo[wn * 32 + 16 + rlo][krow];
    acc[0][0] = __builtin_amdgcn_mfma_f32_16x16x32_bf16(a0, b0, acc[0][0], 0, 0, 0);
    acc[0][1] = __builtin_amdgcn_mfma_f32_16x16x32_bf16(a0, b1, acc[0][1], 0, 0, 0);
    acc[1][0] = __builtin_amdgcn_mfma_f32_16x16x32_bf16(a1, b0, acc[1][0], 0, 0, 0);
    acc[1][1] = __builtin_amdgcn_mfma_f32_16x16x32_bf16(a1, b1, acc[1][1], 0, 0, 0);
    __syncthreads();
  }
#pragma unroll
  for (int mt = 0; mt < 2; mt++)
#pragma unroll
    for (int nt = 0; nt < 2; nt++)
#pragma unroll
      for (int r = 0; r < 4; r++) {
        int l = l0 + wm * 32 + mt * 16 + (lane >> 4) * 4 + r;
        int m = m0 + wn * 32 + nt * 16 + rlo;
        outp[((size_t)b * LL + l) * DM + m] = acc[mt][nt][r];
      }
}

// ---------------------------------------------------------------------------
extern "C" void kernel_launch(void* const* d_in, const int* in_sizes, int n_in,
                              void* d_out, int out_size, void* d_ws, size_t ws_size,
                              hipStream_t stream) {
  (void)in_sizes; (void)n_in; (void)out_size; (void)ws_size;
  const float* A_log = (const float*)d_in[2];
  const float* Ab_log = (const float*)d_in[3];

  float* ws = (float*)d_ws;
  float* xz = ws;                              // BB*DN*LL  (x rows only)
  float* z_t = xz + (size_t)BB * DN * LL;      // BB*LL*DN  silu(z) transposed
  float* u_f = z_t + (size_t)BB * LL * DN;     // BB*LL*DN  (u -> y in place)
  float* u_r = u_f + (size_t)BB * LL * DN;
  float* dl_f = u_r + (size_t)BB * LL * DN;
  float* dl_r = dl_f + (size_t)BB * LL * DN;
  float* B_f = dl_r + (size_t)BB * LL * DN;    // BB*LL*NS
  float* C_f = B_f + (size_t)BB * LL * NS;
  float* B_r = C_f + (size_t)BB * LL * NS;
  float* C_r = B_r + (size_t)BB * LL * NS;
  float* hend = C_r + (size_t)BB * LL * NS;    // NC2*G2*NS
  float* sumdl = hend + (size_t)NC2 * 2 * BB * DN * NS;  // NC2*G2

  for (int s = 0; s < 2; s++) {
    const int p = 4 + s * 14;
    const float* hin = (const float*)d_in[s];
    const float* in_w = (const float*)d_in[p + 0];
    const float* conv_w = (const float*)d_in[p + 1];
    const float* conv_b = (const float*)d_in[p + 2];
    const float* x_w = (const float*)d_in[p + 3];
    const float* dt_w = (const float*)d_in[p + 4];
    const float* dt_b = (const float*)d_in[p + 5];
    const float* Dp = (const float*)d_in[p + 6];
    const float* conv_w_b = (const float*)d_in[p + 7];
    const float* conv_b_b = (const float*)d_in[p + 8];
    const float* x_w_b = (const float*)d_in[p + 9];
    const float* dt_w_b = (const float*)d_in[p + 10];
    const float* dt_b_b = (const float*)d_in[p + 11];
    const float* Dp_b = (const float*)d_in[p + 12];
    const float* out_w = (const float*)d_in[p + 13];
    float* outp = (float*)d_out + (size_t)s * BB * LL * DM;

    hipLaunchKernelGGL(in_proj_mfma, dim3(LL / 128, EE / 128, BB), dim3(256), 0,
                       stream, hin, in_w, xz, z_t);
    hipLaunchKernelGGL(convproj_kernel, dim3(LL / 16, BB, 2), dim3(256), 0, stream,
                       xz, conv_w, conv_b, x_w, dt_w, dt_b, conv_w_b, conv_b_b,
                       x_w_b, dt_w_b, dt_b_b, u_f, dl_f, B_f, C_f, u_r, dl_r, B_r,
                       C_r);
    hipLaunchKernelGGL(HIP_KERNEL_NAME(scan_kernel<1>), dim3(NC2 * 16), dim3(256), 0,
                       stream, u_f, u_r, dl_f, dl_r, z_t, B_f, C_f, B_r, C_r, A_log,
                       Ab_log, Dp, Dp_b, hend, sumdl);
    hipLaunchKernelGGL(scan_combine_kernel, dim3(2 * BB * DN * NS / 256), dim3(256),
                       0, stream, A_log, Ab_log, hend, sumdl);
    hipLaunchKernelGGL(HIP_KERNEL_NAME(scan_kernel<3>), dim3(NC2 * 16), dim3(256), 0,
                       stream, u_f, u_r, dl_f, dl_r, z_t, B_f, C_f, B_r, C_r, A_log,
                       Ab_log, Dp, Dp_b, hend, sumdl);
    hipLaunchKernelGGL(out_proj_mfma, dim3(LL / 64, DM / 64, BB), dim3(256), 0,
                       stream, u_f, u_r, out_w, outp);
  }
}

// Round 8
// 422.302 us; speedup vs baseline: 6.1875x; 1.0124x over previous
//
#include <hip/hip_runtime.h>
#include <hip/hip_bf16.h>
#include <cstddef>

#define BB 4
#define LL 2048
#define DM 256
#define DN 512
#define EE 1024
#define NS 16
#define RK 16
#define NC2 64          // scan chunks
#define CL2 (LL / NC2)  // chunk length = 32

typedef __attribute__((ext_vector_type(8))) short bf16x8;
typedef __attribute__((ext_vector_type(8))) unsigned short ushort8;
typedef __attribute__((ext_vector_type(4))) float f32x4;

__device__ __forceinline__ float fsilu(float x) { return x / (1.0f + __expf(-x)); }
__device__ __forceinline__ float fsoftplus(float x) { return x > 20.0f ? x : log1pf(__expf(x)); }
__device__ __forceinline__ unsigned short f2bf(float x) {  // RNE float->bf16
  union { float f; unsigned int u; } v; v.f = x;
  unsigned int r = v.u + 0x7fffu + ((v.u >> 16) & 1u);
  return (unsigned short)(r >> 16);
}

// ---------------------------------------------------------------------------
// in_proj via bf16 MFMA. Block: 128e x 128l, 4 waves (2x2), wave 64x64 =
// 4x4 MFMA 16x16x32. x-blocks (e<DN): C[e][l] -> xz[b][e][l].
// z-blocks: swap A/B so C[l][d] -> z_t[b][l][d] = silu (coalesced).
// ---------------------------------------------------------------------------
__global__ __launch_bounds__(256) void in_proj_mfma(
    const float* __restrict__ h, const float* __restrict__ w,
    float* __restrict__ xz, float* __restrict__ z_t) {
  __shared__ unsigned short ht[128][40];  // [l][k] bf16, 80B row (16B aligned)
  __shared__ unsigned short wt[128][40];  // [e][k]
  const int b = blockIdx.z;
  const int e0 = blockIdx.y * 128;
  const int l0 = blockIdx.x * 128;
  const int tid = threadIdx.x;
  const int lane = tid & 63;
  const int wid = tid >> 6;
  const int wm = wid >> 1, wn = wid & 1;
  const bool zblk = (e0 >= DN);
  const int krow = (lane >> 4) * 8;
  const int rlo = lane & 15;

  f32x4 acc[4][4];
#pragma unroll
  for (int i = 0; i < 4; i++)
#pragma unroll
    for (int j = 0; j < 4; j++) acc[i][j] = (f32x4){0.f, 0.f, 0.f, 0.f};

  for (int dk = 0; dk < DM; dk += 32) {
#pragma unroll
    for (int it = 0; it < 2; it++) {
      int idx = it * 256 + tid;
      int row = idx >> 2;
      int seg = (idx & 3) * 8;
      const float* hp = h + ((size_t)b * LL + l0 + row) * DM + dk + seg;
      float4 ha = *(const float4*)hp, hb = *(const float4*)(hp + 4);
      ushort8 hv;
      hv[0] = f2bf(ha.x); hv[1] = f2bf(ha.y); hv[2] = f2bf(ha.z); hv[3] = f2bf(ha.w);
      hv[4] = f2bf(hb.x); hv[5] = f2bf(hb.y); hv[6] = f2bf(hb.z); hv[7] = f2bf(hb.w);
      *(ushort8*)&ht[row][seg] = hv;
      const float* wp = w + (size_t)(e0 + row) * DM + dk + seg;
      float4 wa = *(const float4*)wp, wb = *(const float4*)(wp + 4);
      ushort8 wv;
      wv[0] = f2bf(wa.x); wv[1] = f2bf(wa.y); wv[2] = f2bf(wa.z); wv[3] = f2bf(wa.w);
      wv[4] = f2bf(wb.x); wv[5] = f2bf(wb.y); wv[6] = f2bf(wb.z); wv[7] = f2bf(wb.w);
      *(ushort8*)&wt[row][seg] = wv;
    }
    __syncthreads();
    unsigned short (*Ab)[40] = zblk ? ht : wt;
    unsigned short (*Bb)[40] = zblk ? wt : ht;
    bf16x8 af[4], bfr[4];
#pragma unroll
    for (int mt = 0; mt < 4; mt++)
      af[mt] = *(bf16x8*)&Ab[wm * 64 + mt * 16 + rlo][krow];
#pragma unroll
    for (int nt = 0; nt < 4; nt++)
      bfr[nt] = *(bf16x8*)&Bb[wn * 64 + nt * 16 + rlo][krow];
#pragma unroll
    for (int mt = 0; mt < 4; mt++)
#pragma unroll
      for (int nt = 0; nt < 4; nt++)
        acc[mt][nt] = __builtin_amdgcn_mfma_f32_16x16x32_bf16(
            af[mt], bfr[nt], acc[mt][nt], 0, 0, 0);
    __syncthreads();
  }
  if (!zblk) {
#pragma unroll
    for (int mt = 0; mt < 4; mt++)
#pragma unroll
      for (int nt = 0; nt < 4; nt++)
#pragma unroll
        for (int r = 0; r < 4; r++) {
          int e = e0 + wm * 64 + mt * 16 + (lane >> 4) * 4 + r;
          int l = l0 + wn * 64 + nt * 16 + rlo;
          xz[((size_t)b * DN + e) * LL + l] = acc[mt][nt][r];
        }
  } else {
#pragma unroll
    for (int mt = 0; mt < 4; mt++)
#pragma unroll
      for (int nt = 0; nt < 4; nt++)
#pragma unroll
        for (int r = 0; r < 4; r++) {
          int l = l0 + wm * 64 + mt * 16 + (lane >> 4) * 4 + r;
          int d = (e0 - DN) + wn * 64 + nt * 16 + rlo;
          z_t[((size_t)b * LL + l) * DN + d] = fsilu(acc[mt][nt][r]);
        }
  }
}

// ---------------------------------------------------------------------------
// convproj: l-tile 16, 4 waves. conv+silu in VALU; x_dbl via MFMA:
// A = x_w chunk bf16 [48][64], B = conv out bf16 [16 l][64 d]; waves 0-2 own
// m-tiles dt/B/C, K accumulated over 8 chunks of 64. delta stays fp32 VALU.
// ---------------------------------------------------------------------------
__global__ __launch_bounds__(256) void convproj_kernel(
    const float* __restrict__ xz,
    const float* __restrict__ cw_f, const float* __restrict__ cb_f,
    const float* __restrict__ xw_f, const float* __restrict__ dtw_f,
    const float* __restrict__ dtb_f,
    const float* __restrict__ cw_r, const float* __restrict__ cb_r,
    const float* __restrict__ xw_r, const float* __restrict__ dtw_r,
    const float* __restrict__ dtb_r,
    float* __restrict__ u_f, float* __restrict__ dl_f,
    float* __restrict__ B_f, float* __restrict__ C_f,
    float* __restrict__ u_r, float* __restrict__ dl_r,
    float* __restrict__ B_r, float* __restrict__ C_r) {
  __shared__ float xt_c[64][17];          // conv output fp32 chunk [d][l]
  __shared__ unsigned short xtb[16][72];  // conv output bf16 [l][d] (B-frags)
  __shared__ unsigned short xwb[48][72];  // x_w chunk bf16 [r][d]  (A-frags)
  __shared__ float dtv[16][17];           // dt rows fp32
  __shared__ float dtw_c[64][17];         // dt_w chunk
  __shared__ float dtb_s[DN];
  const int rev = blockIdx.z;
  const int b = blockIdx.y;
  const int l0 = blockIdx.x * 16;
  const int tid = threadIdx.x;
  const int lc = tid & 15;
  const int dg = tid >> 4;  // 0..15
  const int l = l0 + lc;
  const int lane = tid & 63;
  const int wv = tid >> 6;  // wave id 0..3
  const int rlo16 = lane & 15;
  const int kseg = (lane >> 4) * 8;

  const float* conv_w = rev ? cw_r : cw_f;
  const float* conv_b = rev ? cb_r : cb_f;
  const float* x_w = rev ? xw_r : xw_f;
  const float* dt_w = rev ? dtw_r : dtw_f;
  const float* dt_b = rev ? dtb_r : dtb_f;
  float* u_out = rev ? u_r : u_f;
  float* dl_out = rev ? dl_r : dl_f;
  float* B_out = rev ? B_r : B_f;
  float* C_out = rev ? C_r : C_f;

  dtb_s[tid] = dt_b[tid];
  dtb_s[tid + 256] = dt_b[tid + 256];

  f32x4 accm = (f32x4){0.f, 0.f, 0.f, 0.f};  // waves 0..2: m-tile accumulator

  for (int dc = 0; dc < 8; dc++) {
    // conv + silu -> xt_c (fp32) + xtb (bf16, [l][d] for B-fragments)
#pragma unroll
    for (int i = 0; i < 4; i++) {
      int dloc = dg * 4 + i;
      int dd = dc * 64 + dloc;
      const float* base = xz + ((size_t)b * DN + dd) * LL;
      float w0 = conv_w[dd * 4 + 0], w1 = conv_w[dd * 4 + 1];
      float w2 = conv_w[dd * 4 + 2], w3 = conv_w[dd * 4 + 3];
      float a0 = conv_b[dd];
      if (rev) {
        a0 = fmaf(w3, base[l], a0);
        if (l + 1 < LL) a0 = fmaf(w2, base[l + 1], a0);
        if (l + 2 < LL) a0 = fmaf(w1, base[l + 2], a0);
        if (l + 3 < LL) a0 = fmaf(w0, base[l + 3], a0);
      } else {
        a0 = fmaf(w3, base[l], a0);
        if (l - 1 >= 0) a0 = fmaf(w2, base[l - 1], a0);
        if (l - 2 >= 0) a0 = fmaf(w1, base[l - 2], a0);
        if (l - 3 >= 0) a0 = fmaf(w0, base[l - 3], a0);
      }
      float uv = fsilu(a0);
      xt_c[dloc][lc] = uv;
      xtb[lc][dloc] = f2bf(uv);
    }
    // stage x_w chunk as bf16 [48][64]
#pragma unroll
    for (int j = 0; j < 12; j++) {
      int idx = j * 256 + tid;
      int r = idx >> 6;
      int k = idx & 63;
      xwb[r][k] = f2bf(x_w[(size_t)r * DN + dc * 64 + k]);
    }
    __syncthreads();
    // u transposed store (coalesced 256B segments)
#pragma unroll
    for (int j = 0; j < 4; j++) {
      int idx = j * 256 + tid;
      int din = idx & 63;
      int l2 = idx >> 6;
      u_out[((size_t)b * LL + l0 + l2) * DN + dc * 64 + din] = xt_c[din][l2];
    }
    // x_dbl partial via MFMA: waves 0..2 = m-tiles (dt, B, C), K=64 (2 steps)
    if (wv < 3) {
      bf16x8 a0 = *(bf16x8*)&xwb[wv * 16 + rlo16][kseg];
      bf16x8 b0 = *(bf16x8*)&xtb[rlo16][kseg];
      accm = __builtin_amdgcn_mfma_f32_16x16x32_bf16(a0, b0, accm, 0, 0, 0);
      bf16x8 a1 = *(bf16x8*)&xwb[wv * 16 + rlo16][32 + kseg];
      bf16x8 b1 = *(bf16x8*)&xtb[rlo16][32 + kseg];
      accm = __builtin_amdgcn_mfma_f32_16x16x32_bf16(a1, b1, accm, 0, 0, 0);
    }
    __syncthreads();
  }
  // unload accumulators: C/D layout col = lane&15 (=l), row = (lane>>4)*4 + r
  {
    const int rbase = (lane >> 4) * 4;
    if (wv == 0) {
#pragma unroll
      for (int r = 0; r < 4; r++) dtv[rbase + r][rlo16] = accm[r];
    } else if (wv == 1) {
#pragma unroll
      for (int r = 0; r < 4; r++)
        B_out[((size_t)b * LL + l0 + rlo16) * NS + rbase + r] = accm[r];
    } else if (wv == 2) {
#pragma unroll
      for (int r = 0; r < 4; r++)
        C_out[((size_t)b * LL + l0 + rlo16) * NS + rbase + r] = accm[r];
    }
  }
  __syncthreads();
  // delta per chunk (exact fp32 path)
  for (int dc = 0; dc < 8; dc++) {
#pragma unroll
    for (int j = 0; j < 4; j++) {
      int idx = j * 256 + tid;
      int row = idx >> 4;
      int k = idx & 15;
      dtw_c[row][k] = dt_w[(size_t)(dc * 64 + row) * RK + k];
    }
    __syncthreads();
#pragma unroll
    for (int i = 0; i < 4; i++) {
      int dloc = dg * 4 + i;
      float a0 = dtb_s[dc * 64 + dloc];
#pragma unroll
      for (int k = 0; k < 16; k++) a0 = fmaf(dtw_c[dloc][k], dtv[k][lc], a0);
      xt_c[dloc][lc] = fsoftplus(a0);
    }
    __syncthreads();
#pragma unroll
    for (int j = 0; j < 4; j++) {
      int idx = j * 256 + tid;
      int din = idx & 63;
      int l2 = idx >> 6;
      dl_out[((size_t)b * LL + l0 + l2) * DN + dc * 64 + din] = xt_c[din][l2];
    }
  }
}

// ---------------------------------------------------------------------------
// Scan: lane = channel d, 16 states in registers. u/delta/z_t/y in [b][t][d]
// (all coalesced), B/C [b][t][n] wave-uniform float4. y in place over u.
// ---------------------------------------------------------------------------
#define HSTEP(n, Bcomp, Ccomp)                      \
  {                                                 \
    float e_ = __expf(dc * Av[n]);                  \
    h[n] = fmaf(e_, h[n], dlu * (Bcomp));           \
    if (PHASE == 3) acc = fmaf(h[n], (Ccomp), acc); \
  }

template <int PHASE>
__global__ __launch_bounds__(256) void scan_kernel(
    float* __restrict__ uy_f, float* __restrict__ uy_r,
    const float* __restrict__ dl_f, const float* __restrict__ dl_r,
    const float* __restrict__ z_t, const float* __restrict__ B_f,
    const float* __restrict__ C_f, const float* __restrict__ B_r,
    const float* __restrict__ C_r, const float* __restrict__ A_log,
    const float* __restrict__ Ab_log, const float* __restrict__ D_f,
    const float* __restrict__ D_r, float* __restrict__ hend,
    float* __restrict__ sumdl) {
  const int G2 = 2 * BB * DN;                            // 4096
  const int ch = (blockIdx.x & 15) * 256 + threadIdx.x;  // channel
  const int chunk = blockIdx.x >> 4;                     // 0..NC2-1
  const bool rev = ch >= BB * DN;                        // uniform per block
  const int cid = rev ? ch - BB * DN : ch;
  const int b = cid >> 9;
  const int d = cid & (DN - 1);

  const float* Arow = (rev ? Ab_log : A_log) + d * NS;
  float Av[NS];
#pragma unroll
  for (int n = 0; n < NS; n++) Av[n] = -__expf(Arow[n]);
  const float Dd = (rev ? D_r : D_f)[d];

  float* uy = (rev ? uy_r : uy_f) + (size_t)b * LL * DN + d;
  const float* dlp = (rev ? dl_r : dl_f) + (size_t)b * LL * DN + d;
  const float* Bp = (rev ? B_r : B_f) + (size_t)b * LL * NS;
  const float* Cp = (rev ? C_r : C_f) + (size_t)b * LL * NS;
  const float* zp = z_t + (size_t)b * LL * DN + d;

  float h[NS];
  if (PHASE == 3) {
    const float* hp = hend + ((size_t)chunk * G2 + ch) * NS;
#pragma unroll
    for (int n = 0; n < NS; n++) h[n] = hp[n];
  } else {
#pragma unroll
    for (int n = 0; n < NS; n++) h[n] = 0.f;
  }

  const int tstep = rev ? -1 : 1;
  int t = rev ? (LL - 1 - CL2 * chunk) : (CL2 * chunk);
  float sdl = 0.f;
  float uc = uy[(size_t)t * DN];
  float dc = dlp[(size_t)t * DN];
  float zc = (PHASE == 3) ? zp[(size_t)t * DN] : 0.f;

  for (int s = 0; s < CL2; s++) {
    int tn = t + tstep;
    int tcl = tn < 0 ? 0 : (tn >= LL ? LL - 1 : tn);
    float un = uy[(size_t)tcl * DN];
    float dn_ = dlp[(size_t)tcl * DN];
    float zn = (PHASE == 3) ? zp[(size_t)tcl * DN] : 0.f;

    const float4* B4 = (const float4*)(Bp + (size_t)t * NS);
    float4 Bq0 = B4[0], Bq1 = B4[1], Bq2 = B4[2], Bq3 = B4[3];
    float4 Cq0 = {0, 0, 0, 0}, Cq1 = {0, 0, 0, 0}, Cq2 = {0, 0, 0, 0},
           Cq3 = {0, 0, 0, 0};
    if (PHASE == 3) {
      const float4* C4 = (const float4*)(Cp + (size_t)t * NS);
      Cq0 = C4[0]; Cq1 = C4[1]; Cq2 = C4[2]; Cq3 = C4[3];
    }
    const float dlu = dc * uc;
    float acc = 0.f;
    HSTEP(0, Bq0.x, Cq0.x)  HSTEP(1, Bq0.y, Cq0.y)
    HSTEP(2, Bq0.z, Cq0.z)  HSTEP(3, Bq0.w, Cq0.w)
    HSTEP(4, Bq1.x, Cq1.x)  HSTEP(5, Bq1.y, Cq1.y)
    HSTEP(6, Bq1.z, Cq1.z)  HSTEP(7, Bq1.w, Cq1.w)
    HSTEP(8, Bq2.x, Cq2.x)  HSTEP(9, Bq2.y, Cq2.y)
    HSTEP(10, Bq2.z, Cq2.z) HSTEP(11, Bq2.w, Cq2.w)
    HSTEP(12, Bq3.x, Cq3.x) HSTEP(13, Bq3.y, Cq3.y)
    HSTEP(14, Bq3.z, Cq3.z) HSTEP(15, Bq3.w, Cq3.w)
    if (PHASE == 1) sdl += dc;
    if (PHASE == 3) {
      float y = fmaf(uc, Dd, acc) * zc;
      uy[(size_t)t * DN] = y;
    }
    t = tn; uc = un; dc = dn_; zc = zn;
  }
  if (PHASE == 1) {
    float* hp = hend + ((size_t)chunk * G2 + ch) * NS;
#pragma unroll
    for (int n = 0; n < NS; n++) hp[n] = h[n];
    sumdl[(size_t)chunk * G2 + ch] = sdl;
  }
}
#undef HSTEP

// Phase 2 (in-place): hend[c] <- h0[c] = H_{c-1}; H_c = exp(Av*sumdl[c])*H + hend[c]
__global__ __launch_bounds__(256) void scan_combine_kernel(
    const float* __restrict__ A_log, const float* __restrict__ Ab_log,
    float* __restrict__ hend, const float* __restrict__ sumdl) {
  const int G2 = 2 * BB * DN;
  const int gtid = blockIdx.x * 256 + threadIdx.x;
  const int ch = gtid >> 4;
  const int n = gtid & 15;
  const bool rev = ch >= BB * DN;
  const int d = ch & (DN - 1);
  const float Av = -__expf((rev ? Ab_log : A_log)[d * NS + n]);
  float H = 0.f;
  for (int c = 0; c < NC2; c++) {
    size_t idx = ((size_t)c * G2 + ch) * NS + n;
    float tmp = hend[idx];
    hend[idx] = H;
    if (c < NC2 - 1)
      H = fmaf(__expf(Av * sumdl[(size_t)c * G2 + ch]), H, tmp);
  }
}

// ---------------------------------------------------------------------------
// out_proj via bf16 MFMA: C[l][m] = sum_d 0.5*(yf+yr)[b][l][d] * ow[m][d].
// Block 64l x 64m, 4 waves (2x2), wave 32x32 = 2x2 MFMA tiles, K=512.
// ---------------------------------------------------------------------------
__global__ __launch_bounds__(256) void out_proj_mfma(
    const float* __restrict__ yf, const float* __restrict__ yr,
    const float* __restrict__ ow, float* __restrict__ outp) {
  __shared__ unsigned short yt[64][40];
  __shared__ unsigned short wo[64][40];
  const int b = blockIdx.z;
  const int m0 = blockIdx.y * 64;
  const int l0 = blockIdx.x * 64;
  const int tid = threadIdx.x;
  const int lane = tid & 63;
  const int wid = tid >> 6;
  const int wm = wid >> 1, wn = wid & 1;
  const int krow = (lane >> 4) * 8;
  const int rlo = lane & 15;

  f32x4 acc[2][2];
#pragma unroll
  for (int i = 0; i < 2; i++)
#pragma unroll
    for (int j = 0; j < 2; j++) acc[i][j] = (f32x4){0.f, 0.f, 0.f, 0.f};

  for (int dk = 0; dk < DN; dk += 32) {
    {
      int row = tid >> 2;
      int seg = (tid & 3) * 8;
      const float* ya = yf + ((size_t)b * LL + l0 + row) * DN + dk + seg;
      const float* yb = yr + ((size_t)b * LL + l0 + row) * DN + dk + seg;
      float4 a0 = *(const float4*)ya, a1 = *(const float4*)(ya + 4);
      float4 b0 = *(const float4*)yb, b1 = *(const float4*)(yb + 4);
      ushort8 yv;
      yv[0] = f2bf(0.5f * (a0.x + b0.x)); yv[1] = f2bf(0.5f * (a0.y + b0.y));
      yv[2] = f2bf(0.5f * (a0.z + b0.z)); yv[3] = f2bf(0.5f * (a0.w + b0.w));
      yv[4] = f2bf(0.5f * (a1.x + b1.x)); yv[5] = f2bf(0.5f * (a1.y + b1.y));
      yv[6] = f2bf(0.5f * (a1.z + b1.z)); yv[7] = f2bf(0.5f * (a1.w + b1.w));
      *(ushort8*)&yt[row][seg] = yv;
      const float* wp = ow + (size_t)(m0 + row) * DN + dk + seg;
      float4 w0 = *(const float4*)wp, w1 = *(const float4*)(wp + 4);
      ushort8 wv;
      wv[0] = f2bf(w0.x); wv[1] = f2bf(w0.y); wv[2] = f2bf(w0.z); wv[3] = f2bf(w0.w);
      wv[4] = f2bf(w1.x); wv[5] = f2bf(w1.y); wv[6] = f2bf(w1.z); wv[7] = f2bf(w1.w);
      *(ushort8*)&wo[row][seg] = wv;
    }
    __syncthreads();
    bf16x8 a0 = *(bf16x8*)&yt[wm * 32 + rlo][krow];
    bf16x8 a1 = *(bf16x8*)&yt[wm * 32 + 16 + rlo][krow];
    bf16x8 b0 = *(bf16x8*)&wo[wn * 32 + rlo][krow];
    bf16x8 b1 = *(bf16x8*)&wo[wn * 32 + 16 + rlo][krow];
    acc[0][0] = __builtin_amdgcn_mfma_f32_16x16x32_bf16(a0, b0, acc[0][0], 0, 0, 0);
    acc[0][1] = __builtin_amdgcn_mfma_f32_16x16x32_bf16(a0, b1, acc[0][1], 0, 0, 0);
    acc[1][0] = __builtin_amdgcn_mfma_f32_16x16x32_bf16(a1, b0, acc[1][0], 0, 0, 0);
    acc[1][1] = __builtin_amdgcn_mfma_f32_16x16x32_bf16(a1, b1, acc[1][1], 0, 0, 0);
    __syncthreads();
  }
#pragma unroll
  for (int mt = 0; mt < 2; mt++)
#pragma unroll
    for (int nt = 0; nt < 2; nt++)
#pragma unroll
      for (int r = 0; r < 4; r++) {
        int l = l0 + wm * 32 + mt * 16 + (lane >> 4) * 4 + r;
        int m = m0 + wn * 32 + nt * 16 + rlo;
        outp[((size_t)b * LL + l) * DM + m] = acc[mt][nt][r];
      }
}

// ---------------------------------------------------------------------------
extern "C" void kernel_launch(void* const* d_in, const int* in_sizes, int n_in,
                              void* d_out, int out_size, void* d_ws, size_t ws_size,
                              hipStream_t stream) {
  (void)in_sizes; (void)n_in; (void)out_size; (void)ws_size;
  const float* A_log = (const float*)d_in[2];
  const float* Ab_log = (const float*)d_in[3];

  float* ws = (float*)d_ws;
  float* xz = ws;                              // BB*DN*LL  (x rows only)
  float* z_t = xz + (size_t)BB * DN * LL;      // BB*LL*DN  silu(z) transposed
  float* u_f = z_t + (size_t)BB * LL * DN;     // BB*LL*DN  (u -> y in place)
  float* u_r = u_f + (size_t)BB * LL * DN;
  float* dl_f = u_r + (size_t)BB * LL * DN;
  float* dl_r = dl_f + (size_t)BB * LL * DN;
  float* B_f = dl_r + (size_t)BB * LL * DN;    // BB*LL*NS
  float* C_f = B_f + (size_t)BB * LL * NS;
  float* B_r = C_f + (size_t)BB * LL * NS;
  float* C_r = B_r + (size_t)BB * LL * NS;
  float* hend = C_r + (size_t)BB * LL * NS;    // NC2*G2*NS
  float* sumdl = hend + (size_t)NC2 * 2 * BB * DN * NS;  // NC2*G2

  for (int s = 0; s < 2; s++) {
    const int p = 4 + s * 14;
    const float* hin = (const float*)d_in[s];
    const float* in_w = (const float*)d_in[p + 0];
    const float* conv_w = (const float*)d_in[p + 1];
    const float* conv_b = (const float*)d_in[p + 2];
    const float* x_w = (const float*)d_in[p + 3];
    const float* dt_w = (const float*)d_in[p + 4];
    const float* dt_b = (const float*)d_in[p + 5];
    const float* Dp = (const float*)d_in[p + 6];
    const float* conv_w_b = (const float*)d_in[p + 7];
    const float* conv_b_b = (const float*)d_in[p + 8];
    const float* x_w_b = (const float*)d_in[p + 9];
    const float* dt_w_b = (const float*)d_in[p + 10];
    const float* dt_b_b = (const float*)d_in[p + 11];
    const float* Dp_b = (const float*)d_in[p + 12];
    const float* out_w = (const float*)d_in[p + 13];
    float* outp = (float*)d_out + (size_t)s * BB * LL * DM;

    hipLaunchKernelGGL(in_proj_mfma, dim3(LL / 128, EE / 128, BB), dim3(256), 0,
                       stream, hin, in_w, xz, z_t);
    hipLaunchKernelGGL(convproj_kernel, dim3(LL / 16, BB, 2), dim3(256), 0, stream,
                       xz, conv_w, conv_b, x_w, dt_w, dt_b, conv_w_b, conv_b_b,
                       x_w_b, dt_w_b, dt_b_b, u_f, dl_f, B_f, C_f, u_r, dl_r, B_r,
                       C_r);
    hipLaunchKernelGGL(HIP_KERNEL_NAME(scan_kernel<1>), dim3(NC2 * 16), dim3(256), 0,
                       stream, u_f, u_r, dl_f, dl_r, z_t, B_f, C_f, B_r, C_r, A_log,
                       Ab_log, Dp, Dp_b, hend, sumdl);
    hipLaunchKernelGGL(scan_combine_kernel, dim3(2 * BB * DN * NS / 256), dim3(256),
                       0, stream, A_log, Ab_log, hend, sumdl);
    hipLaunchKernelGGL(HIP_KERNEL_NAME(scan_kernel<3>), dim3(NC2 * 16), dim3(256), 0,
                       stream, u_f, u_r, dl_f, dl_r, z_t, B_f, C_f, B_r, C_r, A_log,
                       Ab_log, Dp, Dp_b, hend, sumdl);
    hipLaunchKernelGGL(out_proj_mfma, dim3(LL / 64, DM / 64, BB), dim3(256), 0,
                       stream, u_f, u_r, out_w, outp);
  }
}